// Round 11
// baseline (78.305 us; speedup 1.0000x reference)
//
#include <hip/hip_runtime.h>
#include <cstdint>
#include <cstddef>

typedef __bf16 bf16x8 __attribute__((ext_vector_type(8)));
typedef float f32x4 __attribute__((ext_vector_type(4)));

#define B_ 8
#define T_ 2048
#define C_ 1024
#define H_ 128

// C^-0.5 * log2(e): folded into Q at projection; softmax runs in exp2-space.
#define QSC 0.045084220027780106f

__device__ __forceinline__ unsigned short f2bf(float f) {
    __bf16 h = (__bf16)f;
    return *(unsigned short*)&h;
}
__device__ __forceinline__ float bf2f(unsigned short u) {
    union { unsigned int i; float f; } x; x.i = ((unsigned int)u) << 16;
    return x.f;
}

// async global->LDS, 16B per lane. LDS dest must be the wave-uniform base;
// HW adds lane*16. Global src is per-lane.
__device__ __forceinline__ void gload16(void* lds, const void* g) {
    __builtin_amdgcn_global_load_lds(
        (const __attribute__((address_space(1))) unsigned int*)g,
        (__attribute__((address_space(3))) unsigned int*)lds, 16, 0, 0);
}

// ---------------------------------------------------------------------------
// prep_w: WT[which][n][k] bf16  <-  W[k][n] f32.  Row index R = which*128+n.
// ---------------------------------------------------------------------------
__global__ __launch_bounds__(256) void prep_w(
    const float* __restrict__ Wq, const float* __restrict__ Wk,
    const float* __restrict__ Wv, unsigned short* __restrict__ wt)
{
    int gid = blockIdx.x * 256 + threadIdx.x;        // 49152 total
    int which = gid >> 14;
    int rem = gid & 16383;
    int n = rem >> 7;            // 0..127
    int kc = rem & 127;          // k-chunk of 8
    const float* W = which == 0 ? Wq : (which == 1 ? Wk : Wv);
    unsigned short tmp[8];
    #pragma unroll
    for (int i = 0; i < 8; ++i) tmp[i] = f2bf(W[(size_t)(kc * 8 + i) * H_ + n]);
    *(uint4*)&wt[((size_t)which * H_ + n) * C_ + kc * 8] = *(uint4*)tmp;
}

// ---------------------------------------------------------------------------
// proj_fused2: q,k,v for one 64-row m-tile in ONE block (x read once).
// BM=64, BN=384, BK=64. 384 threads = 6 waves, EACH wave computes the full
// 64 rows x its own 64-col band (4x4 fragment acc -> 32 MFMA : 24 ds_read
// per chunk, vs 1:1 before). x staged f32 via gload16 (dbuf 32KB);
// W^T[384][64] bf16 (dbuf 96KB). LDS=128KB -> 1 block/CU, grid 256.
// Epilogue: acc -> LDS (stride 392) -> coalesced stores; Q scaled by QSC,
// V stored transposed [B,H,T].
// ---------------------------------------------------------------------------
__global__ __launch_bounds__(384, 2) void proj_fused2(
    const float* __restrict__ x, const unsigned short* __restrict__ wt,
    const float* __restrict__ bq, const float* __restrict__ bk,
    const float* __restrict__ bv,
    unsigned short* __restrict__ qo, unsigned short* __restrict__ ko,
    unsigned short* __restrict__ vo)
{
    __shared__ float xs[2][64 * 64];             // 32 KB, [m][k] f32, unit-XOR swz
    __shared__ unsigned short ws2[2][384 * 64];  // 96 KB, [R][k] bf16, chunk-XOR swz

    const int tid = threadIdx.x;
    const int w = tid >> 6, l = tid & 63, gl = l >> 4, lc = l & 15;
    const int cb = w * 64;           // this wave's col band
    const int m0 = blockIdx.x * 64;

    f32x4 acc[4][4];
    #pragma unroll
    for (int im = 0; im < 4; ++im)
        #pragma unroll
        for (int jn = 0; jn < 4; ++jn) acc[im][jn] = f32x4{0.f, 0.f, 0.f, 0.f};

    auto stage = [&](int buf, int kc2) {
        const int kb = kc2 * 64;
        // x: 1024 16B units, threads 0..255 (waves 0-3), 4 each — issue FIRST (HBM)
        if (w < 4) {
            #pragma unroll
            for (int ji = 0; ji < 4; ++ji) {
                int slot = ji * 256 + tid;
                int r = slot >> 4, cs = slot & 15;
                gload16(&xs[buf][(ji * 256 + w * 64) * 4],
                        &x[(size_t)(m0 + r) * C_ + kb + ((cs ^ (r & 15)) * 4)]);
            }
        }
        // W^T: 3072 16B units (384 rows x 8 chunks), 8 per thread (L2-hot)
        #pragma unroll
        for (int ji = 0; ji < 8; ++ji) {
            int slot = ji * 384 + tid;
            int R = slot >> 3, cs = slot & 7;
            gload16(&ws2[buf][(ji * 384 + w * 64) * 8],
                    &wt[(size_t)R * C_ + kb + ((cs ^ (R & 7)) * 8)]);
        }
    };

    stage(0, 0);
    __syncthreads();

    int cur = 0;
    for (int kc = 0; kc < 16; ++kc) {
        if (kc < 15) stage(cur ^ 1, kc + 1);
        #pragma unroll
        for (int ks = 0; ks < 2; ++ks) {
            bf16x8 a[4], b[4];
            const int u0 = ks * 8 + gl * 2;
            #pragma unroll
            for (int im = 0; im < 4; ++im) {
                int row = im * 16 + lc;
                f32x4 lo = *(const f32x4*)&xs[cur][(row * 16 + (u0 ^ (row & 15))) * 4];
                f32x4 hi = *(const f32x4*)&xs[cur][(row * 16 + ((u0 + 1) ^ (row & 15))) * 4];
                bf16x8 af;
                af[0] = (__bf16)lo[0]; af[1] = (__bf16)lo[1];
                af[2] = (__bf16)lo[2]; af[3] = (__bf16)lo[3];
                af[4] = (__bf16)hi[0]; af[5] = (__bf16)hi[1];
                af[6] = (__bf16)hi[2]; af[7] = (__bf16)hi[3];
                a[im] = af;
            }
            #pragma unroll
            for (int jn = 0; jn < 4; ++jn) {
                int R = cb + jn * 16 + lc;
                b[jn] = *(const bf16x8*)&ws2[cur][(R * 8 + ((ks * 4 + gl) ^ (R & 7))) * 8];
            }
            #pragma unroll
            for (int im = 0; im < 4; ++im)
                #pragma unroll
                for (int jn = 0; jn < 4; ++jn)
                    acc[im][jn] = __builtin_amdgcn_mfma_f32_16x16x32_bf16(
                        a[im], b[jn], acc[im][jn], 0, 0, 0);
        }
        __syncthreads();
        cur ^= 1;
    }

    // epilogue: acc -> eb (bf16, stride 392 for v-transpose bank spread)
    unsigned short* eb = (unsigned short*)&ws2[0][0];   // 64*392*2 = 50,176 B
    #pragma unroll
    for (int jn = 0; jn < 4; ++jn) {
        int n = cb + jn * 16 + lc;
        int wh = n >> 7, nl = n & 127;
        float bb = (wh == 0) ? bq[nl] : (wh == 1 ? bk[nl] : bv[nl]);
        float sc = (wh == 0) ? QSC : 1.0f;
        #pragma unroll
        for (int im = 0; im < 4; ++im)
            #pragma unroll
            for (int r = 0; r < 4; ++r) {
                int row = im * 16 + gl * 4 + r;
                eb[row * 392 + n] = f2bf((acc[im][jn][r] + bb) * sc);
            }
    }
    __syncthreads();

    const int bi = m0 >> 11, t0 = m0 & (T_ - 1);
    #pragma unroll
    for (int i = 0; i < 3; ++i) {
        int c = i * 384 + tid;                 // 0..1151, use 0..1023
        if (c < 1024) {
            // q,k: [64 rows][128 cols] -> 16B chunks
            {
                int row = c >> 4, c16 = c & 15;
                *(uint4*)&qo[(size_t)(m0 + row) * H_ + c16 * 8] =
                    *(const uint4*)&eb[row * 392 + c16 * 8];
                *(uint4*)&ko[(size_t)(m0 + row) * H_ + c16 * 8] =
                    *(const uint4*)&eb[row * 392 + 128 + c16 * 8];
            }
            // v transposed: vT[n][t0+cc*8..+7] from eb[t][256+n]
            {
                int n = c >> 3, cc = c & 7;
                unsigned short tmp[8];
                #pragma unroll
                for (int ii = 0; ii < 8; ++ii)
                    tmp[ii] = eb[(cc * 8 + ii) * 392 + 256 + n];
                *(uint4*)&vo[((size_t)(bi * H_ + n)) * T_ + t0 + cc * 8] = *(uint4*)tmp;
            }
        }
    }
}

// pasc(qt) = number of jobs for q-tiles < qt (QBLK=64, chunk=256):
// nch(i) = ceil((i+1)/4); pasc = 2m(m+1) + j(m+1), m=qt>>2, j=qt&3.
__device__ __forceinline__ int pasc(int qt) {
    int m = qt >> 2, j = qt & 3;
    return 2 * m * (m + 1) + j * (m + 1);
}

// ---------------------------------------------------------------------------
// attn_split7: KV-split flash attention, 4 waves (QBLK=64) sharing K/V LDS.
// grid (8 batch=XCD pin, 144 jobs). KVBLK=32, chunk=256 keys.
// LDS = 16+16+8 = 40KB -> 4 blocks/CU = 16 waves/CU resident.
// No-max exp2 softmax; bf16 partials; plain-sum combine.
// ---------------------------------------------------------------------------
__global__ __launch_bounds__(256, 2) void attn_split7(
    const unsigned short* __restrict__ q,
    const unsigned short* __restrict__ k,
    const unsigned short* __restrict__ vT,
    float* __restrict__ out,
    unsigned short* __restrict__ Opart, float* __restrict__ lws)
{
    const int bb = blockIdx.x;                 // batch -> XCD pin
    const int jj = 143 - (int)blockIdx.y;      // longest jobs first
    int qt = 31;
    while (pasc(qt) > jj) --qt;
    const int c = jj - pasc(qt);
    const int nch = (qt >> 2) + 1;
    const int q0 = qt * 64;
    const int kstart = c * 256;
    const int kend = min(kstart + 256, q0 + 64);
    const int ntiles = (kend - kstart) >> 5;   // 1..8

    const unsigned short* qb = q  + (size_t)bb * T_ * H_;
    const unsigned short* kb = k  + (size_t)bb * T_ * H_;
    const unsigned short* vb = vT + (size_t)bb * H_ * T_;

    __shared__ unsigned short Ks[2][32 * 128];   // [key][d], chunk-XOR swizzled
    __shared__ unsigned short Vs[2][128 * 32];   // [d][key], chunk-XOR swizzled
    __shared__ unsigned short Ps[4][16 * 64];    // per-wave P

    const int tid = threadIdx.x;
    const int w = tid >> 6, l = tid & 63, gl = l >> 4, lc = l & 15;
    const int rowbase = q0 + w * 16;             // this wave's first q row

    bf16x8 aq[4];
    #pragma unroll
    for (int ds = 0; ds < 4; ++ds)
        aq[ds] = *(const bf16x8*)&qb[(size_t)(rowbase + lc) * H_ + ds * 32 + gl * 8];

    f32x4 o[8];
    #pragma unroll
    for (int jo = 0; jo < 8; ++jo) o[jo] = f32x4{0.f, 0.f, 0.f, 0.f};
    float l_acc[4];
    #pragma unroll
    for (int r = 0; r < 4; ++r) l_acc[r] = 0.f;

    auto stageK = [&](int buf, int t) {
        const int kv0 = kstart + t * 32;
        #pragma unroll
        for (int ji = 0; ji < 2; ++ji) {
            int slot = (w * 2 + ji) * 64 + l;
            int r = slot >> 4, cs = slot & 15;
            gload16(&Ks[buf][((w * 2 + ji) * 64) * 8],
                    &kb[(size_t)(kv0 + r) * H_ + ((cs ^ (r & 7)) * 8)]);
        }
    };
    auto stageV = [&](int buf, int t) {
        const int kv0 = kstart + t * 32;
        #pragma unroll
        for (int ji = 0; ji < 2; ++ji) {
            int slot = (w * 2 + ji) * 64 + l;
            int r = slot >> 2, cs = slot & 3;
            gload16(&Vs[buf][((w * 2 + ji) * 64) * 8],
                    &vb[(size_t)r * T_ + kv0 + ((cs ^ (r & 3)) * 8)]);
        }
    };

    stageK(0, 0);
    stageV(0, 0);
    __syncthreads();

    int cur = 0;
    for (int t = 0; t < ntiles; ++t) {
        if (t + 1 < ntiles) { stageK(cur ^ 1, t + 1); stageV(cur ^ 1, t + 1); }
        const int kv0 = kstart + t * 32;
        const bool active = kv0 < rowbase + 16;
        if (active) {
            f32x4 s[2];
            #pragma unroll
            for (int jk = 0; jk < 2; ++jk) s[jk] = f32x4{0.f, 0.f, 0.f, 0.f};
            #pragma unroll
            for (int ds = 0; ds < 4; ++ds) {
                #pragma unroll
                for (int jk = 0; jk < 2; ++jk) {
                    int row = jk * 16 + lc;
                    bf16x8 kf = *(const bf16x8*)&Ks[cur][(row * 16 + ((ds * 4 + gl) ^ (row & 7))) * 8];
                    s[jk] = __builtin_amdgcn_mfma_f32_16x16x32_bf16(aq[ds], kf, s[jk], 0, 0, 0);
                }
            }
            if (kv0 + 31 > rowbase) {
                #pragma unroll
                for (int jk = 0; jk < 2; ++jk)
                    #pragma unroll
                    for (int r = 0; r < 4; ++r)
                        if (kv0 + jk * 16 + lc > rowbase + gl * 4 + r) s[jk][r] = -1e30f;
            }
            #pragma unroll
            for (int jk = 0; jk < 2; ++jk)
                #pragma unroll
                for (int r = 0; r < 4; ++r) {
                    float p = exp2f(fminf(s[jk][r], 80.f));
                    s[jk][r] = p;
                    l_acc[r] += p;
                }
            #pragma unroll
            for (int jk = 0; jk < 2; ++jk)
                #pragma unroll
                for (int r = 0; r < 4; ++r) {
                    int row = gl * 4 + r;
                    Ps[w][(row * 64 + jk * 16 + lc) ^ ((row & 7) << 3)] = f2bf(s[jk][r]);
                }
            {
                bf16x8 pa = *(const bf16x8*)&Ps[w][(lc * 64 + gl * 8) ^ ((lc & 7) << 3)];
                #pragma unroll
                for (int jo = 0; jo < 8; ++jo) {
                    int d = jo * 16 + lc;
                    bf16x8 vf = *(const bf16x8*)&Vs[cur][(d * 4 + (gl ^ (d & 3))) * 8];
                    o[jo] = __builtin_amdgcn_mfma_f32_16x16x32_bf16(pa, vf, o[jo], 0, 0, 0);
                }
            }
        }
        __syncthreads();
        cur ^= 1;
    }

    #pragma unroll
    for (int off = 1; off < 16; off <<= 1)
        #pragma unroll
        for (int r = 0; r < 4; ++r)
            l_acc[r] += __shfl_xor(l_acc[r], off, 64);

    if (nch == 1) {
        float* ob = out + (size_t)bb * T_ * H_;
        float inv[4];
        #pragma unroll
        for (int r = 0; r < 4; ++r) inv[r] = 1.0f / l_acc[r];
        #pragma unroll
        for (int jo = 0; jo < 8; ++jo)
            #pragma unroll
            for (int r = 0; r < 4; ++r)
                ob[(size_t)(rowbase + gl * 4 + r) * H_ + jo * 16 + lc] = o[jo][r] * inv[r];
    } else {
        const int slot = bb * 140 + (pasc(qt) - 4 + c);
        unsigned short* op = Opart + (size_t)slot * 8192;
        #pragma unroll
        for (int jo = 0; jo < 8; ++jo)
            #pragma unroll
            for (int r = 0; r < 4; ++r)
                op[(w * 16 + gl * 4 + r) * 128 + jo * 16 + lc] = f2bf(o[jo][r]);
        if (lc == 0) {
            #pragma unroll
            for (int r = 0; r < 4; ++r)
                lws[slot * 64 + w * 16 + gl * 4 + r] = l_acc[r];
        }
    }
}

// ---------------------------------------------------------------------------
// combine: out[t] = sum_c O_c[t] / sum_c l_c[t] for t >= 256 (bf16 partials).
// ---------------------------------------------------------------------------
__global__ __launch_bounds__(256) void combine_kernel(
    const unsigned short* __restrict__ Opart, const float* __restrict__ lws,
    float* __restrict__ out)
{
    const int rowid = blockIdx.x * 4 + (threadIdx.x >> 6);   // 0..14335
    const int lane = threadIdx.x & 63;
    const int bb = rowid / 1792;
    const int t = 256 + (rowid - bb * 1792);                 // 256..2047
    const int qt = t >> 6;                                    // 4..31
    const int m = qt >> 2;
    const int nch = m + 1;
    const int p0 = 2 * m * (m + 1) + (qt & 3) * (m + 1);     // pasc(qt)
    const int base = bb * 140 + (p0 - 4);
    const int r64 = t & 63;

    float L = 0.f, a0 = 0.f, a1 = 0.f;
    #pragma unroll
    for (int c2 = 0; c2 < 8; ++c2)
        if (c2 < nch) {
            L += lws[(base + c2) * 64 + r64];
            ushort2 uv = *(const ushort2*)&Opart[(size_t)(base + c2) * 8192 + r64 * 128 + lane * 2];
            a0 += bf2f(uv.x); a1 += bf2f(uv.y);
        }
    const float invL = 1.0f / L;
    *(float2*)&out[((size_t)bb * T_ + t) * H_ + lane * 2] = make_float2(a0 * invL, a1 * invL);
}

// ---------------------------------------------------------------------------
// Fallback monolithic attention (only if ws too small). Max-tracking version.
// ---------------------------------------------------------------------------
__global__ __launch_bounds__(128) void attn_mono(
    const unsigned short* __restrict__ q,
    const unsigned short* __restrict__ k,
    const unsigned short* __restrict__ vT,
    float* __restrict__ out)
{
    const int qt = (gridDim.x - 1) - blockIdx.x;
    const int bb = blockIdx.y;
    const int q0 = qt * 32;
    const unsigned short* qb = q  + (size_t)bb * T_ * H_;
    const unsigned short* kb = k  + (size_t)bb * T_ * H_;
    const unsigned short* vb = vT + (size_t)bb * H_ * T_;

    __shared__ unsigned short Ps[2][16 * 64];

    const int tid = threadIdx.x;
    const int w = tid >> 6, l = tid & 63, gl = l >> 4, lc = l & 15;

    bf16x8 aq[4];
    #pragma unroll
    for (int ds = 0; ds < 4; ++ds)
        aq[ds] = *(const bf16x8*)&qb[(size_t)(q0 + w * 16 + lc) * H_ + ds * 32 + gl * 8];

    f32x4 o[8];
    #pragma unroll
    for (int jo = 0; jo < 8; ++jo) o[jo] = f32x4{0.f, 0.f, 0.f, 0.f};
    float m_run[4], l_run[4];
    #pragma unroll
    for (int r = 0; r < 4; ++r) { m_run[r] = -INFINITY; l_run[r] = 0.f; }

    const int nt = (q0 >> 6) + 1;
    for (int t = 0; t < nt; ++t) {
        const int kv0 = t * 64;
        f32x4 s[4];
        #pragma unroll
        for (int jk = 0; jk < 4; ++jk) s[jk] = f32x4{0.f, 0.f, 0.f, 0.f};
        #pragma unroll
        for (int ds = 0; ds < 4; ++ds)
            #pragma unroll
            for (int jk = 0; jk < 4; ++jk) {
                bf16x8 bf = *(const bf16x8*)&kb[(size_t)(kv0 + jk * 16 + lc) * H_ + ds * 32 + gl * 8];
                s[jk] = __builtin_amdgcn_mfma_f32_16x16x32_bf16(aq[ds], bf, s[jk], 0, 0, 0);
            }
        if (kv0 + 63 > q0) {
            const int rowg = q0 + w * 16 + gl * 4;
            #pragma unroll
            for (int jk = 0; jk < 4; ++jk)
                #pragma unroll
                for (int r = 0; r < 4; ++r)
                    if (kv0 + jk * 16 + lc > rowg + r) s[jk][r] = -1e30f;
        }
        float pm[4];
        #pragma unroll
        for (int r = 0; r < 4; ++r)
            pm[r] = fmaxf(fmaxf(s[0][r], s[1][r]), fmaxf(s[2][r], s[3][r]));
        #pragma unroll
        for (int off = 1; off < 16; off <<= 1)
            #pragma unroll
            for (int r = 0; r < 4; ++r)
                pm[r] = fmaxf(pm[r], __shfl_xor(pm[r], off, 64));
        float scl[4], rs[4];
        #pragma unroll
        for (int r = 0; r < 4; ++r) {
            float mn = fmaxf(m_run[r], pm[r]);
            scl[r] = exp2f(m_run[r] - mn);
            m_run[r] = mn;
            rs[r] = 0.f;
        }
        #pragma unroll
        for (int jk = 0; jk < 4; ++jk)
            #pragma unroll
            for (int r = 0; r < 4; ++r) {
                float p = exp2f(s[jk][r] - m_run[r]);
                s[jk][r] = p;
                rs[r] += p;
            }
        #pragma unroll
        for (int off = 1; off < 16; off <<= 1)
            #pragma unroll
            for (int r = 0; r < 4; ++r)
                rs[r] += __shfl_xor(rs[r], off, 64);
        #pragma unroll
        for (int r = 0; r < 4; ++r)
            l_run[r] = l_run[r] * scl[r] + rs[r];
        #pragma unroll
        for (int jo = 0; jo < 8; ++jo)
            #pragma unroll
            for (int r = 0; r < 4; ++r)
                o[jo][r] *= scl[r];
        #pragma unroll
        for (int jk = 0; jk < 4; ++jk)
            #pragma unroll
            for (int r = 0; r < 4; ++r) {
                int row = gl * 4 + r;
                Ps[w][(row * 64 + jk * 16 + lc) ^ ((row & 7) << 3)] = f2bf(s[jk][r]);
            }
        #pragma unroll
        for (int ks = 0; ks < 2; ++ks) {
            bf16x8 pa = *(const bf16x8*)&Ps[w][(lc * 64 + ks * 32 + gl * 8) ^ ((lc & 7) << 3)];
            #pragma unroll
            for (int jo = 0; jo < 8; ++jo) {
                bf16x8 bv_ = *(const bf16x8*)&vb[(size_t)(jo * 16 + lc) * T_ + kv0 + ks * 32 + gl * 8];
                o[jo] = __builtin_amdgcn_mfma_f32_16x16x32_bf16(pa, bv_, o[jo], 0, 0, 0);
            }
        }
    }
    float* ob = out + (size_t)bb * T_ * H_;
    #pragma unroll
    for (int jo = 0; jo < 8; ++jo)
        #pragma unroll
        for (int r = 0; r < 4; ++r)
            ob[(size_t)(q0 + w * 16 + gl * 4 + r) * H_ + jo * 16 + lc] = o[jo][r] / l_run[r];
}

extern "C" void kernel_launch(void* const* d_in, const int* in_sizes, int n_in,
                              void* d_out, int out_size, void* d_ws, size_t ws_size,
                              hipStream_t stream) {
    const float* x  = (const float*)d_in[0];
    const float* Wq = (const float*)d_in[1];
    const float* bq = (const float*)d_in[2];
    const float* Wk = (const float*)d_in[3];
    const float* bk = (const float*)d_in[4];
    const float* Wv = (const float*)d_in[5];
    const float* bv = (const float*)d_in[6];
    float* out = (float*)d_out;

    const size_t qkv = (size_t)B_ * T_ * H_;               // 2M elems
    unsigned short* qws = (unsigned short*)d_ws;
    unsigned short* kws = qws + qkv;
    unsigned short* vws = kws + qkv;                       // [B,H,T] transposed
    unsigned short* wtw = vws + qkv;                       // [3,H,C]
    const size_t base_bytes = (3 * qkv + (size_t)3 * H_ * C_) * 2;  // 13,369,344
    unsigned short* Opart = (unsigned short*)((char*)d_ws + base_bytes);  // 1120 x 8192 bf16
    float* lws = (float*)((char*)d_ws + base_bytes + (size_t)1120 * 8192 * 2);
    const size_t need = base_bytes + (size_t)1120 * 8192 * 2 + (size_t)1120 * 64 * 4;

    prep_w<<<dim3(192), 256, 0, stream>>>(Wq, Wk, Wv, wtw);
    proj_fused2<<<dim3(256), 384, 0, stream>>>(x, wtw, bq, bk, bv, qws, kws, vws);
    if (ws_size >= need) {
        attn_split7<<<dim3(8, 144), 256, 0, stream>>>(qws, kws, vws, out, Opart, lws);
        combine_kernel<<<dim3(3584), 256, 0, stream>>>(Opart, lws, out);
    } else {
        attn_mono<<<dim3(64, 8), 128, 0, stream>>>(qws, kws, vws, out);
    }
}

// Round 12
// 72.314 us; speedup vs baseline: 1.0828x; 1.0828x over previous
//
#include <hip/hip_runtime.h>
#include <cstdint>
#include <cstddef>

typedef __bf16 bf16x8 __attribute__((ext_vector_type(8)));
typedef float f32x4 __attribute__((ext_vector_type(4)));

#define B_ 8
#define T_ 2048
#define C_ 1024
#define H_ 128

// C^-0.5 * log2(e): folded into Q at projection; softmax runs in exp2-space.
#define QSC 0.045084220027780106f

__device__ __forceinline__ unsigned short f2bf(float f) {
    __bf16 h = (__bf16)f;
    return *(unsigned short*)&h;
}
__device__ __forceinline__ float bf2f(unsigned short u) {
    union { unsigned int i; float f; } x; x.i = ((unsigned int)u) << 16;
    return x.f;
}

// async global->LDS, 16B per lane. LDS dest must be the wave-uniform base;
// HW adds lane*16. Global src is per-lane.
__device__ __forceinline__ void gload16(void* lds, const void* g) {
    __builtin_amdgcn_global_load_lds(
        (const __attribute__((address_space(1))) unsigned int*)g,
        (__attribute__((address_space(3))) unsigned int*)lds, 16, 0, 0);
}

// ---------------------------------------------------------------------------
// prep_w: WT[which][n][k] bf16  <-  W[k][n] f32.  Row index R = which*128+n.
// ---------------------------------------------------------------------------
__global__ __launch_bounds__(256) void prep_w(
    const float* __restrict__ Wq, const float* __restrict__ Wk,
    const float* __restrict__ Wv, unsigned short* __restrict__ wt)
{
    int gid = blockIdx.x * 256 + threadIdx.x;        // 49152 total
    int which = gid >> 14;
    int rem = gid & 16383;
    int n = rem >> 7;            // 0..127
    int kc = rem & 127;          // k-chunk of 8
    const float* W = which == 0 ? Wq : (which == 1 ? Wk : Wv);
    unsigned short tmp[8];
    #pragma unroll
    for (int i = 0; i < 8; ++i) tmp[i] = f2bf(W[(size_t)(kc * 8 + i) * H_ + n]);
    *(uint4*)&wt[((size_t)which * H_ + n) * C_ + kc * 8] = *(uint4*)tmp;
}

// ---------------------------------------------------------------------------
// proj_fused3: q,k,v for one 64-row m-tile in ONE block, COUNTED-VMCNT
// pipeline (no vmcnt(0) drain in the steady loop). BM=64, BN=384, BK=64.
// 512 threads = 8 waves, each owns 64 rows x 48 cols (4x3 fragments).
// Per chunk each thread issues EXACTLY 8 gload16 (x:2 + W:6) -> vmcnt(8)
// at the staging barrier keeps the next-next chunk's loads in flight while
// guaranteeing the next chunk's landed. 2-deep prefetch, raw s_barrier.
// LDS: x f32 dbuf 32KB + W^T dbuf 96KB = 128KB -> 1 block/CU, grid 256.
// Epilogue: acc -> LDS (stride 392) -> coalesced stores; Q scaled by QSC,
// V stored transposed [B,H,T].
// ---------------------------------------------------------------------------
__global__ __launch_bounds__(512, 2) void proj_fused3(
    const float* __restrict__ x, const unsigned short* __restrict__ wt,
    const float* __restrict__ bq, const float* __restrict__ bk,
    const float* __restrict__ bv,
    unsigned short* __restrict__ qo, unsigned short* __restrict__ ko,
    unsigned short* __restrict__ vo)
{
    __shared__ float xs[2][64 * 64];             // 32 KB, [m][k] f32, unit-XOR swz
    __shared__ unsigned short ws2[2][384 * 64];  // 96 KB, [R][k] bf16, chunk-XOR swz

    const int tid = threadIdx.x;
    const int w = tid >> 6, l = tid & 63, gl = l >> 4, lc = l & 15;
    const int cb = w * 48;           // this wave's col band (3 jn tiles)
    const int m0 = blockIdx.x * 64;

    f32x4 acc[4][3];
    #pragma unroll
    for (int im = 0; im < 4; ++im)
        #pragma unroll
        for (int jn = 0; jn < 3; ++jn) acc[im][jn] = f32x4{0.f, 0.f, 0.f, 0.f};

    // stage one K-chunk: exactly 8 gload16 per thread (x:2 then W:6)
    auto stage = [&](int buf, int kc2) {
        const int kb = kc2 * 64;
        #pragma unroll
        for (int ji = 0; ji < 2; ++ji) {           // x: 1024 16B units (HBM) first
            int slot = ji * 512 + tid;
            int r = slot >> 4, cs = slot & 15;
            gload16(&xs[buf][(ji * 512 + w * 64) * 4],
                    &x[(size_t)(m0 + r) * C_ + kb + ((cs ^ (r & 15)) * 4)]);
        }
        #pragma unroll
        for (int ji = 0; ji < 6; ++ji) {           // W^T: 3072 16B units (L2-hot)
            int slot = ji * 512 + tid;
            int R = slot >> 3, cs = slot & 7;
            gload16(&ws2[buf][(ji * 512 + w * 64) * 8],
                    &wt[(size_t)R * C_ + kb + ((cs ^ (R & 7)) * 8)]);
        }
    };

    // prologue: 2-deep prefetch
    stage(0, 0);
    stage(1, 1);
    asm volatile("s_waitcnt vmcnt(8)" ::: "memory");   // chunk 0 landed
    __builtin_amdgcn_sched_barrier(0);
    __builtin_amdgcn_s_barrier();

    for (int kc = 0; kc < 16; ++kc) {
        const int cur = kc & 1;
        #pragma unroll
        for (int ks = 0; ks < 2; ++ks) {
            bf16x8 a[4], b[3];
            const int u0 = ks * 8 + gl * 2;
            #pragma unroll
            for (int im = 0; im < 4; ++im) {
                int row = im * 16 + lc;            // row & 15 == lc
                f32x4 lo = *(const f32x4*)&xs[cur][(row * 16 + (u0 ^ lc)) * 4];
                f32x4 hi = *(const f32x4*)&xs[cur][(row * 16 + ((u0 + 1) ^ lc)) * 4];
                bf16x8 af;
                af[0] = (__bf16)lo[0]; af[1] = (__bf16)lo[1];
                af[2] = (__bf16)lo[2]; af[3] = (__bf16)lo[3];
                af[4] = (__bf16)hi[0]; af[5] = (__bf16)hi[1];
                af[6] = (__bf16)hi[2]; af[7] = (__bf16)hi[3];
                a[im] = af;
            }
            #pragma unroll
            for (int jn = 0; jn < 3; ++jn) {
                int R = cb + jn * 16 + lc;         // R & 7 == lc & 7
                b[jn] = *(const bf16x8*)&ws2[cur][(R * 8 + ((ks * 4 + gl) ^ (lc & 7))) * 8];
            }
            #pragma unroll
            for (int im = 0; im < 4; ++im)
                #pragma unroll
                for (int jn = 0; jn < 3; ++jn)
                    acc[im][jn] = __builtin_amdgcn_mfma_f32_16x16x32_bf16(
                        a[im], b[jn], acc[im][jn], 0, 0, 0);
        }
        // barrier #1: all waves done READING buf cur (lgkm waited before MFMAs)
        __builtin_amdgcn_s_barrier();
        if (kc < 14) {
            stage(cur, kc + 2);                    // overwrite cur (2-deep)
            // wait for chunk kc+1's loads (older than the 8 just issued)
            asm volatile("s_waitcnt vmcnt(8)" ::: "memory");
            __builtin_amdgcn_sched_barrier(0);
            __builtin_amdgcn_s_barrier();          // barrier #2: next buf ready
        } else if (kc == 14) {
            asm volatile("s_waitcnt vmcnt(0)" ::: "memory");
            __builtin_amdgcn_sched_barrier(0);
            __builtin_amdgcn_s_barrier();
        }
        // kc == 15: fall through (barrier #1 already passed) to epilogue
    }

    // epilogue: acc -> eb (bf16, stride 392 for v-transpose bank spread)
    unsigned short* eb = (unsigned short*)&ws2[0][0];   // 64*392*2 = 50,176 B
    #pragma unroll
    for (int jn = 0; jn < 3; ++jn) {
        int n = cb + jn * 16 + lc;
        int wh = n >> 7, nl = n & 127;
        float bb = (wh == 0) ? bq[nl] : (wh == 1 ? bk[nl] : bv[nl]);
        float sc = (wh == 0) ? QSC : 1.0f;
        #pragma unroll
        for (int im = 0; im < 4; ++im)
            #pragma unroll
            for (int r = 0; r < 4; ++r) {
                int row = im * 16 + gl * 4 + r;
                eb[row * 392 + n] = f2bf((acc[im][jn][r] + bb) * sc);
            }
    }
    __syncthreads();

    const int bi = m0 >> 11, t0 = m0 & (T_ - 1);
    #pragma unroll
    for (int i = 0; i < 2; ++i) {
        int c = i * 512 + tid;                 // 0..1023
        // q,k: [64 rows][128 cols] -> 16B chunks
        {
            int row = c >> 4, c16 = c & 15;
            *(uint4*)&qo[(size_t)(m0 + row) * H_ + c16 * 8] =
                *(const uint4*)&eb[row * 392 + c16 * 8];
            *(uint4*)&ko[(size_t)(m0 + row) * H_ + c16 * 8] =
                *(const uint4*)&eb[row * 392 + 128 + c16 * 8];
        }
        // v transposed: vT[n][t0+cc*8..+7] from eb[t][256+n]
        {
            int n = c >> 3, cc = c & 7;
            unsigned short tmp[8];
            #pragma unroll
            for (int ii = 0; ii < 8; ++ii)
                tmp[ii] = eb[(cc * 8 + ii) * 392 + 256 + n];
            *(uint4*)&vo[((size_t)(bi * H_ + n)) * T_ + t0 + cc * 8] = *(uint4*)tmp;
        }
    }
}

// pasc(qt) = number of jobs for q-tiles < qt (QBLK=64, chunk=256):
// nch(i) = ceil((i+1)/4); pasc = 2m(m+1) + j(m+1), m=qt>>2, j=qt&3.
__device__ __forceinline__ int pasc(int qt) {
    int m = qt >> 2, j = qt & 3;
    return 2 * m * (m + 1) + j * (m + 1);
}

// ---------------------------------------------------------------------------
// attn_split7: KV-split flash attention, 4 waves (QBLK=64) sharing K/V LDS.
// grid (8 batch=XCD pin, 144 jobs). KVBLK=32, chunk=256 keys.
// LDS = 16+16+8 = 40KB -> 4 blocks/CU = 16 waves/CU resident.
// No-max exp2 softmax; bf16 partials; plain-sum combine.
// ---------------------------------------------------------------------------
__global__ __launch_bounds__(256, 2) void attn_split7(
    const unsigned short* __restrict__ q,
    const unsigned short* __restrict__ k,
    const unsigned short* __restrict__ vT,
    float* __restrict__ out,
    unsigned short* __restrict__ Opart, float* __restrict__ lws)
{
    const int bb = blockIdx.x;                 // batch -> XCD pin
    const int jj = 143 - (int)blockIdx.y;      // longest jobs first
    int qt = 31;
    while (pasc(qt) > jj) --qt;
    const int c = jj - pasc(qt);
    const int nch = (qt >> 2) + 1;
    const int q0 = qt * 64;
    const int kstart = c * 256;
    const int kend = min(kstart + 256, q0 + 64);
    const int ntiles = (kend - kstart) >> 5;   // 1..8

    const unsigned short* qb = q  + (size_t)bb * T_ * H_;
    const unsigned short* kb = k  + (size_t)bb * T_ * H_;
    const unsigned short* vb = vT + (size_t)bb * H_ * T_;

    __shared__ unsigned short Ks[2][32 * 128];   // [key][d], chunk-XOR swizzled
    __shared__ unsigned short Vs[2][128 * 32];   // [d][key], chunk-XOR swizzled
    __shared__ unsigned short Ps[4][16 * 64];    // per-wave P

    const int tid = threadIdx.x;
    const int w = tid >> 6, l = tid & 63, gl = l >> 4, lc = l & 15;
    const int rowbase = q0 + w * 16;             // this wave's first q row

    bf16x8 aq[4];
    #pragma unroll
    for (int ds = 0; ds < 4; ++ds)
        aq[ds] = *(const bf16x8*)&qb[(size_t)(rowbase + lc) * H_ + ds * 32 + gl * 8];

    f32x4 o[8];
    #pragma unroll
    for (int jo = 0; jo < 8; ++jo) o[jo] = f32x4{0.f, 0.f, 0.f, 0.f};
    float l_acc[4];
    #pragma unroll
    for (int r = 0; r < 4; ++r) l_acc[r] = 0.f;

    auto stageK = [&](int buf, int t) {
        const int kv0 = kstart + t * 32;
        #pragma unroll
        for (int ji = 0; ji < 2; ++ji) {
            int slot = (w * 2 + ji) * 64 + l;
            int r = slot >> 4, cs = slot & 15;
            gload16(&Ks[buf][((w * 2 + ji) * 64) * 8],
                    &kb[(size_t)(kv0 + r) * H_ + ((cs ^ (r & 7)) * 8)]);
        }
    };
    auto stageV = [&](int buf, int t) {
        const int kv0 = kstart + t * 32;
        #pragma unroll
        for (int ji = 0; ji < 2; ++ji) {
            int slot = (w * 2 + ji) * 64 + l;
            int r = slot >> 2, cs = slot & 3;
            gload16(&Vs[buf][((w * 2 + ji) * 64) * 8],
                    &vb[(size_t)r * T_ + kv0 + ((cs ^ (r & 3)) * 8)]);
        }
    };

    stageK(0, 0);
    stageV(0, 0);
    __syncthreads();

    int cur = 0;
    for (int t = 0; t < ntiles; ++t) {
        if (t + 1 < ntiles) { stageK(cur ^ 1, t + 1); stageV(cur ^ 1, t + 1); }
        const int kv0 = kstart + t * 32;
        const bool active = kv0 < rowbase + 16;
        if (active) {
            f32x4 s[2];
            #pragma unroll
            for (int jk = 0; jk < 2; ++jk) s[jk] = f32x4{0.f, 0.f, 0.f, 0.f};
            #pragma unroll
            for (int ds = 0; ds < 4; ++ds) {
                #pragma unroll
                for (int jk = 0; jk < 2; ++jk) {
                    int row = jk * 16 + lc;
                    bf16x8 kf = *(const bf16x8*)&Ks[cur][(row * 16 + ((ds * 4 + gl) ^ (row & 7))) * 8];
                    s[jk] = __builtin_amdgcn_mfma_f32_16x16x32_bf16(aq[ds], kf, s[jk], 0, 0, 0);
                }
            }
            if (kv0 + 31 > rowbase) {
                #pragma unroll
                for (int jk = 0; jk < 2; ++jk)
                    #pragma unroll
                    for (int r = 0; r < 4; ++r)
                        if (kv0 + jk * 16 + lc > rowbase + gl * 4 + r) s[jk][r] = -1e30f;
            }
            #pragma unroll
            for (int jk = 0; jk < 2; ++jk)
                #pragma unroll
                for (int r = 0; r < 4; ++r) {
                    float p = exp2f(fminf(s[jk][r], 80.f));
                    s[jk][r] = p;
                    l_acc[r] += p;
                }
            #pragma unroll
            for (int jk = 0; jk < 2; ++jk)
                #pragma unroll
                for (int r = 0; r < 4; ++r) {
                    int row = gl * 4 + r;
                    Ps[w][(row * 64 + jk * 16 + lc) ^ ((row & 7) << 3)] = f2bf(s[jk][r]);
                }
            {
                bf16x8 pa = *(const bf16x8*)&Ps[w][(lc * 64 + gl * 8) ^ ((lc & 7) << 3)];
                #pragma unroll
                for (int jo = 0; jo < 8; ++jo) {
                    int d = jo * 16 + lc;
                    bf16x8 vf = *(const bf16x8*)&Vs[cur][(d * 4 + (gl ^ (d & 3))) * 8];
                    o[jo] = __builtin_amdgcn_mfma_f32_16x16x32_bf16(pa, vf, o[jo], 0, 0, 0);
                }
            }
        }
        __syncthreads();
        cur ^= 1;
    }

    #pragma unroll
    for (int off = 1; off < 16; off <<= 1)
        #pragma unroll
        for (int r = 0; r < 4; ++r)
            l_acc[r] += __shfl_xor(l_acc[r], off, 64);

    if (nch == 1) {
        float* ob = out + (size_t)bb * T_ * H_;
        float inv[4];
        #pragma unroll
        for (int r = 0; r < 4; ++r) inv[r] = 1.0f / l_acc[r];
        #pragma unroll
        for (int jo = 0; jo < 8; ++jo)
            #pragma unroll
            for (int r = 0; r < 4; ++r)
                ob[(size_t)(rowbase + gl * 4 + r) * H_ + jo * 16 + lc] = o[jo][r] * inv[r];
    } else {
        const int slot = bb * 140 + (pasc(qt) - 4 + c);
        unsigned short* op = Opart + (size_t)slot * 8192;
        #pragma unroll
        for (int jo = 0; jo < 8; ++jo)
            #pragma unroll
            for (int r = 0; r < 4; ++r)
                op[(w * 16 + gl * 4 + r) * 128 + jo * 16 + lc] = f2bf(o[jo][r]);
        if (lc == 0) {
            #pragma unroll
            for (int r = 0; r < 4; ++r)
                lws[slot * 64 + w * 16 + gl * 4 + r] = l_acc[r];
        }
    }
}

// ---------------------------------------------------------------------------
// combine: out[t] = sum_c O_c[t] / sum_c l_c[t] for t >= 256 (bf16 partials).
// ---------------------------------------------------------------------------
__global__ __launch_bounds__(256) void combine_kernel(
    const unsigned short* __restrict__ Opart, const float* __restrict__ lws,
    float* __restrict__ out)
{
    const int rowid = blockIdx.x * 4 + (threadIdx.x >> 6);   // 0..14335
    const int lane = threadIdx.x & 63;
    const int bb = rowid / 1792;
    const int t = 256 + (rowid - bb * 1792);                 // 256..2047
    const int qt = t >> 6;                                    // 4..31
    const int m = qt >> 2;
    const int nch = m + 1;
    const int p0 = 2 * m * (m + 1) + (qt & 3) * (m + 1);     // pasc(qt)
    const int base = bb * 140 + (p0 - 4);
    const int r64 = t & 63;

    float L = 0.f, a0 = 0.f, a1 = 0.f;
    #pragma unroll
    for (int c2 = 0; c2 < 8; ++c2)
        if (c2 < nch) {
            L += lws[(base + c2) * 64 + r64];
            ushort2 uv = *(const ushort2*)&Opart[(size_t)(base + c2) * 8192 + r64 * 128 + lane * 2];
            a0 += bf2f(uv.x); a1 += bf2f(uv.y);
        }
    const float invL = 1.0f / L;
    *(float2*)&out[((size_t)bb * T_ + t) * H_ + lane * 2] = make_float2(a0 * invL, a1 * invL);
}

// ---------------------------------------------------------------------------
// Fallback monolithic attention (only if ws too small). Max-tracking version.
// ---------------------------------------------------------------------------
__global__ __launch_bounds__(128) void attn_mono(
    const unsigned short* __restrict__ q,
    const unsigned short* __restrict__ k,
    const unsigned short* __restrict__ vT,
    float* __restrict__ out)
{
    const int qt = (gridDim.x - 1) - blockIdx.x;
    const int bb = blockIdx.y;
    const int q0 = qt * 32;
    const unsigned short* qb = q  + (size_t)bb * T_ * H_;
    const unsigned short* kb = k  + (size_t)bb * T_ * H_;
    const unsigned short* vb = vT + (size_t)bb * H_ * T_;

    __shared__ unsigned short Ps[2][16 * 64];

    const int tid = threadIdx.x;
    const int w = tid >> 6, l = tid & 63, gl = l >> 4, lc = l & 15;

    bf16x8 aq[4];
    #pragma unroll
    for (int ds = 0; ds < 4; ++ds)
        aq[ds] = *(const bf16x8*)&qb[(size_t)(q0 + w * 16 + lc) * H_ + ds * 32 + gl * 8];

    f32x4 o[8];
    #pragma unroll
    for (int jo = 0; jo < 8; ++jo) o[jo] = f32x4{0.f, 0.f, 0.f, 0.f};
    float m_run[4], l_run[4];
    #pragma unroll
    for (int r = 0; r < 4; ++r) { m_run[r] = -INFINITY; l_run[r] = 0.f; }

    const int nt = (q0 >> 6) + 1;
    for (int t = 0; t < nt; ++t) {
        const int kv0 = t * 64;
        f32x4 s[4];
        #pragma unroll
        for (int jk = 0; jk < 4; ++jk) s[jk] = f32x4{0.f, 0.f, 0.f, 0.f};
        #pragma unroll
        for (int ds = 0; ds < 4; ++ds)
            #pragma unroll
            for (int jk = 0; jk < 4; ++jk) {
                bf16x8 bf = *(const bf16x8*)&kb[(size_t)(kv0 + jk * 16 + lc) * H_ + ds * 32 + gl * 8];
                s[jk] = __builtin_amdgcn_mfma_f32_16x16x32_bf16(aq[ds], bf, s[jk], 0, 0, 0);
            }
        if (kv0 + 63 > q0) {
            const int rowg = q0 + w * 16 + gl * 4;
            #pragma unroll
            for (int jk = 0; jk < 4; ++jk)
                #pragma unroll
                for (int r = 0; r < 4; ++r)
                    if (kv0 + jk * 16 + lc > rowg + r) s[jk][r] = -1e30f;
        }
        float pm[4];
        #pragma unroll
        for (int r = 0; r < 4; ++r)
            pm[r] = fmaxf(fmaxf(s[0][r], s[1][r]), fmaxf(s[2][r], s[3][r]));
        #pragma unroll
        for (int off = 1; off < 16; off <<= 1)
            #pragma unroll
            for (int r = 0; r < 4; ++r)
                pm[r] = fmaxf(pm[r], __shfl_xor(pm[r], off, 64));
        float scl[4], rs[4];
        #pragma unroll
        for (int r = 0; r < 4; ++r) {
            float mn = fmaxf(m_run[r], pm[r]);
            scl[r] = exp2f(m_run[r] - mn);
            m_run[r] = mn;
            rs[r] = 0.f;
        }
        #pragma unroll
        for (int jk = 0; jk < 4; ++jk)
            #pragma unroll
            for (int r = 0; r < 4; ++r) {
                float p = exp2f(s[jk][r] - m_run[r]);
                s[jk][r] = p;
                rs[r] += p;
            }
        #pragma unroll
        for (int off = 1; off < 16; off <<= 1)
            #pragma unroll
            for (int r = 0; r < 4; ++r)
                rs[r] += __shfl_xor(rs[r], off, 64);
        #pragma unroll
        for (int r = 0; r < 4; ++r)
            l_run[r] = l_run[r] * scl[r] + rs[r];
        #pragma unroll
        for (int jo = 0; jo < 8; ++jo)
            #pragma unroll
            for (int r = 0; r < 4; ++r)
                o[jo][r] *= scl[r];
        #pragma unroll
        for (int jk = 0; jk < 4; ++jk)
            #pragma unroll
            for (int r = 0; r < 4; ++r) {
                int row = gl * 4 + r;
                Ps[w][(row * 64 + jk * 16 + lc) ^ ((row & 7) << 3)] = f2bf(s[jk][r]);
            }
        #pragma unroll
        for (int ks = 0; ks < 2; ++ks) {
            bf16x8 pa = *(const bf16x8*)&Ps[w][(lc * 64 + ks * 32 + gl * 8) ^ ((lc & 7) << 3)];
            #pragma unroll
            for (int jo = 0; jo < 8; ++jo) {
                bf16x8 bv_ = *(const bf16x8*)&vb[(size_t)(jo * 16 + lc) * T_ + kv0 + ks * 32 + gl * 8];
                o[jo] = __builtin_amdgcn_mfma_f32_16x16x32_bf16(pa, bv_, o[jo], 0, 0, 0);
            }
        }
    }
    float* ob = out + (size_t)bb * T_ * H_;
    #pragma unroll
    for (int jo = 0; jo < 8; ++jo)
        #pragma unroll
        for (int r = 0; r < 4; ++r)
            ob[(size_t)(q0 + w * 16 + gl * 4 + r) * H_ + jo * 16 + lc] = o[jo][r] / l_run[r];
}

extern "C" void kernel_launch(void* const* d_in, const int* in_sizes, int n_in,
                              void* d_out, int out_size, void* d_ws, size_t ws_size,
                              hipStream_t stream) {
    const float* x  = (const float*)d_in[0];
    const float* Wq = (const float*)d_in[1];
    const float* bq = (const float*)d_in[2];
    const float* Wk = (const float*)d_in[3];
    const float* bk = (const float*)d_in[4];
    const float* Wv = (const float*)d_in[5];
    const float* bv = (const float*)d_in[6];
    float* out = (float*)d_out;

    const size_t qkv = (size_t)B_ * T_ * H_;               // 2M elems
    unsigned short* qws = (unsigned short*)d_ws;
    unsigned short* kws = qws + qkv;
    unsigned short* vws = kws + qkv;                       // [B,H,T] transposed
    unsigned short* wtw = vws + qkv;                       // [3,H,C]
    const size_t base_bytes = (3 * qkv + (size_t)3 * H_ * C_) * 2;  // 13,369,344
    unsigned short* Opart = (unsigned short*)((char*)d_ws + base_bytes);  // 1120 x 8192 bf16
    float* lws = (float*)((char*)d_ws + base_bytes + (size_t)1120 * 8192 * 2);
    const size_t need = base_bytes + (size_t)1120 * 8192 * 2 + (size_t)1120 * 64 * 4;

    prep_w<<<dim3(192), 256, 0, stream>>>(Wq, Wk, Wv, wtw);
    proj_fused3<<<dim3(256), 512, 0, stream>>>(x, wtw, bq, bk, bv, qws, kws, vws);
    if (ws_size >= need) {
        attn_split7<<<dim3(8, 144), 256, 0, stream>>>(qws, kws, vws, out, Opart, lws);
        combine_kernel<<<dim3(3584), 256, 0, stream>>>(Opart, lws, out);
    } else {
        attn_mono<<<dim3(64, 8), 128, 0, stream>>>(qws, kws, vws, out);
    }
}

// Round 13
// 69.550 us; speedup vs baseline: 1.1259x; 1.0397x over previous
//
#include <hip/hip_runtime.h>
#include <cstdint>
#include <cstddef>

typedef __bf16 bf16x8 __attribute__((ext_vector_type(8)));
typedef float f32x4 __attribute__((ext_vector_type(4)));

#define B_ 8
#define T_ 2048
#define C_ 1024
#define H_ 128

// C^-0.5 * log2(e): folded into Q at projection; softmax runs in exp2-space.
#define QSC 0.045084220027780106f

__device__ __forceinline__ unsigned short f2bf(float f) {
    __bf16 h = (__bf16)f;
    return *(unsigned short*)&h;
}
__device__ __forceinline__ float bf2f(unsigned short u) {
    union { unsigned int i; float f; } x; x.i = ((unsigned int)u) << 16;
    return x.f;
}

// async global->LDS, 16B per lane. LDS dest must be the wave-uniform base;
// HW adds lane*16. Global src is per-lane.
__device__ __forceinline__ void gload16(void* lds, const void* g) {
    __builtin_amdgcn_global_load_lds(
        (const __attribute__((address_space(1))) unsigned int*)g,
        (__attribute__((address_space(3))) unsigned int*)lds, 16, 0, 0);
}

// ---------------------------------------------------------------------------
// prep_w: WT[which][n][k] bf16  <-  W[k][n] f32.  Row index R = which*128+n.
// ---------------------------------------------------------------------------
__global__ __launch_bounds__(256) void prep_w(
    const float* __restrict__ Wq, const float* __restrict__ Wk,
    const float* __restrict__ Wv, unsigned short* __restrict__ wt)
{
    int gid = blockIdx.x * 256 + threadIdx.x;        // 49152 total
    int which = gid >> 14;
    int rem = gid & 16383;
    int n = rem >> 7;            // 0..127
    int kc = rem & 127;          // k-chunk of 8
    const float* W = which == 0 ? Wq : (which == 1 ? Wk : Wv);
    unsigned short tmp[8];
    #pragma unroll
    for (int i = 0; i < 8; ++i) tmp[i] = f2bf(W[(size_t)(kc * 8 + i) * H_ + n]);
    *(uint4*)&wt[((size_t)which * H_ + n) * C_ + kc * 8] = *(uint4*)tmp;
}

// ---------------------------------------------------------------------------
// proj_fused4: 2-family fused projection. Family f computes cols
// [f*192, f*192+192) of the q|k|v concatenation for one 64-row m-tile.
// BM=64, BN=192, BK=64. 256 threads = 4 waves, each wave owns 64 rows x
// 48 cols (4x3 fragments). Counted-vmcnt pipeline (N=10: x 4 + W 6 gload16
// per thread per chunk), 2-deep prefetch, raw barriers. LDS = x f32 dbuf
// 32KB + W^T[192][64] dbuf 48KB = 80KB -> 2 blocks/CU (two independent
// barrier domains per CU). Grid (256, 2). Both families co-resident ->
// second x read L2/L3-served.
// Epilogue: acc -> LDS (stride 200) -> coalesced stores; Q scaled by QSC,
// V stored transposed [B,H,T].
// ---------------------------------------------------------------------------
__global__ __launch_bounds__(256, 2) void proj_fused4(
    const float* __restrict__ x, const unsigned short* __restrict__ wt,
    const float* __restrict__ bq, const float* __restrict__ bk,
    const float* __restrict__ bv,
    unsigned short* __restrict__ qo, unsigned short* __restrict__ ko,
    unsigned short* __restrict__ vo)
{
    __shared__ float xs[2][64 * 64];             // 32 KB, [m][k] f32, unit-XOR swz
    __shared__ unsigned short ws2[2][192 * 64];  // 48 KB, [R][k] bf16, chunk-XOR swz

    const int tid = threadIdx.x;
    const int w = tid >> 6, l = tid & 63, gl = l >> 4, lc = l & 15;
    const int cb = w * 48;           // this wave's col band within the family
    const int fam = blockIdx.y;
    const int m0 = blockIdx.x * 64;
    const unsigned short* wbase = wt + (size_t)fam * 192 * C_;

    f32x4 acc[4][3];
    #pragma unroll
    for (int im = 0; im < 4; ++im)
        #pragma unroll
        for (int jn = 0; jn < 3; ++jn) acc[im][jn] = f32x4{0.f, 0.f, 0.f, 0.f};

    // stage one K-chunk: exactly 10 gload16 per thread (x:4 then W:6)
    auto stage = [&](int buf, int kc2) {
        const int kb = kc2 * 64;
        #pragma unroll
        for (int ji = 0; ji < 4; ++ji) {           // x: 1024 16B units (HBM) first
            int slot = ji * 256 + tid;
            int r = slot >> 4, cs = slot & 15;
            gload16(&xs[buf][(ji * 256 + w * 64) * 4],
                    &x[(size_t)(m0 + r) * C_ + kb + ((cs ^ (r & 15)) * 4)]);
        }
        #pragma unroll
        for (int ji = 0; ji < 6; ++ji) {           // W^T: 1536 16B units (L2-hot)
            int slot = ji * 256 + tid;
            int R = slot >> 3, cs = slot & 7;
            gload16(&ws2[buf][(ji * 256 + w * 64) * 8],
                    &wbase[(size_t)R * C_ + kb + ((cs ^ (R & 7)) * 8)]);
        }
    };

    // prologue: 2-deep prefetch
    stage(0, 0);
    stage(1, 1);
    asm volatile("s_waitcnt vmcnt(10)" ::: "memory");   // chunk 0 landed
    __builtin_amdgcn_sched_barrier(0);
    __builtin_amdgcn_s_barrier();

    for (int kc = 0; kc < 16; ++kc) {
        const int cur = kc & 1;
        #pragma unroll
        for (int ks = 0; ks < 2; ++ks) {
            bf16x8 a[4], b[3];
            const int u0 = ks * 8 + gl * 2;
            #pragma unroll
            for (int im = 0; im < 4; ++im) {
                int row = im * 16 + lc;            // row & 15 == lc
                f32x4 lo = *(const f32x4*)&xs[cur][(row * 16 + (u0 ^ lc)) * 4];
                f32x4 hi = *(const f32x4*)&xs[cur][(row * 16 + ((u0 + 1) ^ lc)) * 4];
                bf16x8 af;
                af[0] = (__bf16)lo[0]; af[1] = (__bf16)lo[1];
                af[2] = (__bf16)lo[2]; af[3] = (__bf16)lo[3];
                af[4] = (__bf16)hi[0]; af[5] = (__bf16)hi[1];
                af[6] = (__bf16)hi[2]; af[7] = (__bf16)hi[3];
                a[im] = af;
            }
            #pragma unroll
            for (int jn = 0; jn < 3; ++jn) {
                int R = cb + jn * 16 + lc;         // R & 7 == lc & 7
                b[jn] = *(const bf16x8*)&ws2[cur][(R * 8 + ((ks * 4 + gl) ^ (lc & 7))) * 8];
            }
            #pragma unroll
            for (int im = 0; im < 4; ++im)
                #pragma unroll
                for (int jn = 0; jn < 3; ++jn)
                    acc[im][jn] = __builtin_amdgcn_mfma_f32_16x16x32_bf16(
                        a[im], b[jn], acc[im][jn], 0, 0, 0);
        }
        // barrier #1: all waves done READING buf cur
        __builtin_amdgcn_s_barrier();
        if (kc < 14) {
            stage(cur, kc + 2);                    // overwrite cur (2-deep)
            asm volatile("s_waitcnt vmcnt(10)" ::: "memory");  // chunk kc+1 landed
            __builtin_amdgcn_sched_barrier(0);
            __builtin_amdgcn_s_barrier();          // barrier #2: next buf ready
        } else if (kc == 14) {
            asm volatile("s_waitcnt vmcnt(0)" ::: "memory");
            __builtin_amdgcn_sched_barrier(0);
            __builtin_amdgcn_s_barrier();
        }
        // kc == 15: fall through to epilogue (barrier #1 already passed)
    }

    // epilogue: acc -> eb (bf16, stride 200 = 192+8 for bank spread)
    unsigned short* eb = (unsigned short*)&ws2[0][0];   // 64*200*2 = 25.6 KB
    #pragma unroll
    for (int jn = 0; jn < 3; ++jn) {
        int nl_ = cb + jn * 16 + lc;               // 0..191 (family-local)
        int ng = fam * 192 + nl_;                  // 0..383 global col
        int wh = ng >> 7, nn = ng & 127;
        float bb = (wh == 0) ? bq[nn] : (wh == 1 ? bk[nn] : bv[nn]);
        float sc = (wh == 0) ? QSC : 1.0f;
        #pragma unroll
        for (int im = 0; im < 4; ++im)
            #pragma unroll
            for (int r = 0; r < 4; ++r) {
                int row = im * 16 + gl * 4 + r;
                eb[row * 200 + nl_] = f2bf((acc[im][jn][r] + bb) * sc);
            }
    }
    __syncthreads();

    const int bi = m0 >> 11, t0 = m0 & (T_ - 1);
    if (fam == 0) {
        // q full (cols 0..127): 1024 uint4
        #pragma unroll
        for (int i = 0; i < 4; ++i) {
            int c = i * 256 + tid;
            int row = c >> 4, c16 = c & 15;
            *(uint4*)&qo[(size_t)(m0 + row) * H_ + c16 * 8] =
                *(const uint4*)&eb[row * 200 + c16 * 8];
        }
        // k cols 0..63 (eb cols 128..191): 512 uint4
        #pragma unroll
        for (int i = 0; i < 2; ++i) {
            int c = i * 256 + tid;
            int row = c >> 3, c8 = c & 7;
            *(uint4*)&ko[(size_t)(m0 + row) * H_ + c8 * 8] =
                *(const uint4*)&eb[row * 200 + 128 + c8 * 8];
        }
    } else {
        // k cols 64..127 (eb cols 0..63): 512 uint4
        #pragma unroll
        for (int i = 0; i < 2; ++i) {
            int c = i * 256 + tid;
            int row = c >> 3, c8 = c & 7;
            *(uint4*)&ko[(size_t)(m0 + row) * H_ + 64 + c8 * 8] =
                *(const uint4*)&eb[row * 200 + c8 * 8];
        }
        // v (cols 256..383 -> eb cols 64..191), stored transposed
        #pragma unroll
        for (int i = 0; i < 4; ++i) {
            int c = i * 256 + tid;
            int n = c >> 3, cc = c & 7;
            unsigned short tmp[8];
            #pragma unroll
            for (int ii = 0; ii < 8; ++ii)
                tmp[ii] = eb[(cc * 8 + ii) * 200 + 64 + n];
            *(uint4*)&vo[((size_t)(bi * H_ + n)) * T_ + t0 + cc * 8] = *(uint4*)tmp;
        }
    }
}

// pasc(qt) = number of jobs for q-tiles < qt (QBLK=64, chunk=256):
// nch(i) = ceil((i+1)/4); pasc = 2m(m+1) + j(m+1), m=qt>>2, j=qt&3.
__device__ __forceinline__ int pasc(int qt) {
    int m = qt >> 2, j = qt & 3;
    return 2 * m * (m + 1) + j * (m + 1);
}

// ---------------------------------------------------------------------------
// attn_split7: KV-split flash attention, 4 waves (QBLK=64) sharing K/V LDS.
// grid (8 batch=XCD pin, 144 jobs). KVBLK=32, chunk=256 keys.
// LDS = 16+16+8 = 40KB -> 4 blocks/CU = 16 waves/CU resident.
// No-max exp2 softmax; bf16 partials; plain-sum combine.
// ---------------------------------------------------------------------------
__global__ __launch_bounds__(256, 2) void attn_split7(
    const unsigned short* __restrict__ q,
    const unsigned short* __restrict__ k,
    const unsigned short* __restrict__ vT,
    float* __restrict__ out,
    unsigned short* __restrict__ Opart, float* __restrict__ lws)
{
    const int bb = blockIdx.x;                 // batch -> XCD pin
    const int jj = 143 - (int)blockIdx.y;      // longest jobs first
    int qt = 31;
    while (pasc(qt) > jj) --qt;
    const int c = jj - pasc(qt);
    const int nch = (qt >> 2) + 1;
    const int q0 = qt * 64;
    const int kstart = c * 256;
    const int kend = min(kstart + 256, q0 + 64);
    const int ntiles = (kend - kstart) >> 5;   // 1..8

    const unsigned short* qb = q  + (size_t)bb * T_ * H_;
    const unsigned short* kb = k  + (size_t)bb * T_ * H_;
    const unsigned short* vb = vT + (size_t)bb * H_ * T_;

    __shared__ unsigned short Ks[2][32 * 128];   // [key][d], chunk-XOR swizzled
    __shared__ unsigned short Vs[2][128 * 32];   // [d][key], chunk-XOR swizzled
    __shared__ unsigned short Ps[4][16 * 64];    // per-wave P

    const int tid = threadIdx.x;
    const int w = tid >> 6, l = tid & 63, gl = l >> 4, lc = l & 15;
    const int rowbase = q0 + w * 16;             // this wave's first q row

    bf16x8 aq[4];
    #pragma unroll
    for (int ds = 0; ds < 4; ++ds)
        aq[ds] = *(const bf16x8*)&qb[(size_t)(rowbase + lc) * H_ + ds * 32 + gl * 8];

    f32x4 o[8];
    #pragma unroll
    for (int jo = 0; jo < 8; ++jo) o[jo] = f32x4{0.f, 0.f, 0.f, 0.f};
    float l_acc[4];
    #pragma unroll
    for (int r = 0; r < 4; ++r) l_acc[r] = 0.f;

    auto stageK = [&](int buf, int t) {
        const int kv0 = kstart + t * 32;
        #pragma unroll
        for (int ji = 0; ji < 2; ++ji) {
            int slot = (w * 2 + ji) * 64 + l;
            int r = slot >> 4, cs = slot & 15;
            gload16(&Ks[buf][((w * 2 + ji) * 64) * 8],
                    &kb[(size_t)(kv0 + r) * H_ + ((cs ^ (r & 7)) * 8)]);
        }
    };
    auto stageV = [&](int buf, int t) {
        const int kv0 = kstart + t * 32;
        #pragma unroll
        for (int ji = 0; ji < 2; ++ji) {
            int slot = (w * 2 + ji) * 64 + l;
            int r = slot >> 2, cs = slot & 3;
            gload16(&Vs[buf][((w * 2 + ji) * 64) * 8],
                    &vb[(size_t)r * T_ + kv0 + ((cs ^ (r & 3)) * 8)]);
        }
    };

    stageK(0, 0);
    stageV(0, 0);
    __syncthreads();

    int cur = 0;
    for (int t = 0; t < ntiles; ++t) {
        if (t + 1 < ntiles) { stageK(cur ^ 1, t + 1); stageV(cur ^ 1, t + 1); }
        const int kv0 = kstart + t * 32;
        const bool active = kv0 < rowbase + 16;
        if (active) {
            f32x4 s[2];
            #pragma unroll
            for (int jk = 0; jk < 2; ++jk) s[jk] = f32x4{0.f, 0.f, 0.f, 0.f};
            #pragma unroll
            for (int ds = 0; ds < 4; ++ds) {
                #pragma unroll
                for (int jk = 0; jk < 2; ++jk) {
                    int row = jk * 16 + lc;
                    bf16x8 kf = *(const bf16x8*)&Ks[cur][(row * 16 + ((ds * 4 + gl) ^ (row & 7))) * 8];
                    s[jk] = __builtin_amdgcn_mfma_f32_16x16x32_bf16(aq[ds], kf, s[jk], 0, 0, 0);
                }
            }
            if (kv0 + 31 > rowbase) {
                #pragma unroll
                for (int jk = 0; jk < 2; ++jk)
                    #pragma unroll
                    for (int r = 0; r < 4; ++r)
                        if (kv0 + jk * 16 + lc > rowbase + gl * 4 + r) s[jk][r] = -1e30f;
            }
            #pragma unroll
            for (int jk = 0; jk < 2; ++jk)
                #pragma unroll
                for (int r = 0; r < 4; ++r) {
                    float p = exp2f(fminf(s[jk][r], 80.f));
                    s[jk][r] = p;
                    l_acc[r] += p;
                }
            #pragma unroll
            for (int jk = 0; jk < 2; ++jk)
                #pragma unroll
                for (int r = 0; r < 4; ++r) {
                    int row = gl * 4 + r;
                    Ps[w][(row * 64 + jk * 16 + lc) ^ ((row & 7) << 3)] = f2bf(s[jk][r]);
                }
            {
                bf16x8 pa = *(const bf16x8*)&Ps[w][(lc * 64 + gl * 8) ^ ((lc & 7) << 3)];
                #pragma unroll
                for (int jo = 0; jo < 8; ++jo) {
                    int d = jo * 16 + lc;
                    bf16x8 vf = *(const bf16x8*)&Vs[cur][(d * 4 + (gl ^ (d & 3))) * 8];
                    o[jo] = __builtin_amdgcn_mfma_f32_16x16x32_bf16(pa, vf, o[jo], 0, 0, 0);
                }
            }
        }
        __syncthreads();
        cur ^= 1;
    }

    #pragma unroll
    for (int off = 1; off < 16; off <<= 1)
        #pragma unroll
        for (int r = 0; r < 4; ++r)
            l_acc[r] += __shfl_xor(l_acc[r], off, 64);

    if (nch == 1) {
        float* ob = out + (size_t)bb * T_ * H_;
        float inv[4];
        #pragma unroll
        for (int r = 0; r < 4; ++r) inv[r] = 1.0f / l_acc[r];
        #pragma unroll
        for (int jo = 0; jo < 8; ++jo)
            #pragma unroll
            for (int r = 0; r < 4; ++r)
                ob[(size_t)(rowbase + gl * 4 + r) * H_ + jo * 16 + lc] = o[jo][r] * inv[r];
    } else {
        const int slot = bb * 140 + (pasc(qt) - 4 + c);
        unsigned short* op = Opart + (size_t)slot * 8192;
        #pragma unroll
        for (int jo = 0; jo < 8; ++jo)
            #pragma unroll
            for (int r = 0; r < 4; ++r)
                op[(w * 16 + gl * 4 + r) * 128 + jo * 16 + lc] = f2bf(o[jo][r]);
        if (lc == 0) {
            #pragma unroll
            for (int r = 0; r < 4; ++r)
                lws[slot * 64 + w * 16 + gl * 4 + r] = l_acc[r];
        }
    }
}

// ---------------------------------------------------------------------------
// combine: out[t] = sum_c O_c[t] / sum_c l_c[t] for t >= 256 (bf16 partials).
// ---------------------------------------------------------------------------
__global__ __launch_bounds__(256) void combine_kernel(
    const unsigned short* __restrict__ Opart, const float* __restrict__ lws,
    float* __restrict__ out)
{
    const int rowid = blockIdx.x * 4 + (threadIdx.x >> 6);   // 0..14335
    const int lane = threadIdx.x & 63;
    const int bb = rowid / 1792;
    const int t = 256 + (rowid - bb * 1792);                 // 256..2047
    const int qt = t >> 6;                                    // 4..31
    const int m = qt >> 2;
    const int nch = m + 1;
    const int p0 = 2 * m * (m + 1) + (qt & 3) * (m + 1);     // pasc(qt)
    const int base = bb * 140 + (p0 - 4);
    const int r64 = t & 63;

    float L = 0.f, a0 = 0.f, a1 = 0.f;
    #pragma unroll
    for (int c2 = 0; c2 < 8; ++c2)
        if (c2 < nch) {
            L += lws[(base + c2) * 64 + r64];
            ushort2 uv = *(const ushort2*)&Opart[(size_t)(base + c2) * 8192 + r64 * 128 + lane * 2];
            a0 += bf2f(uv.x); a1 += bf2f(uv.y);
        }
    const float invL = 1.0f / L;
    *(float2*)&out[((size_t)bb * T_ + t) * H_ + lane * 2] = make_float2(a0 * invL, a1 * invL);
}

// ---------------------------------------------------------------------------
// Fallback monolithic attention (only if ws too small). Max-tracking version.
// ---------------------------------------------------------------------------
__global__ __launch_bounds__(128) void attn_mono(
    const unsigned short* __restrict__ q,
    const unsigned short* __restrict__ k,
    const unsigned short* __restrict__ vT,
    float* __restrict__ out)
{
    const int qt = (gridDim.x - 1) - blockIdx.x;
    const int bb = blockIdx.y;
    const int q0 = qt * 32;
    const unsigned short* qb = q  + (size_t)bb * T_ * H_;
    const unsigned short* kb = k  + (size_t)bb * T_ * H_;
    const unsigned short* vb = vT + (size_t)bb * H_ * T_;

    __shared__ unsigned short Ps[2][16 * 64];

    const int tid = threadIdx.x;
    const int w = tid >> 6, l = tid & 63, gl = l >> 4, lc = l & 15;

    bf16x8 aq[4];
    #pragma unroll
    for (int ds = 0; ds < 4; ++ds)
        aq[ds] = *(const bf16x8*)&qb[(size_t)(q0 + w * 16 + lc) * H_ + ds * 32 + gl * 8];

    f32x4 o[8];
    #pragma unroll
    for (int jo = 0; jo < 8; ++jo) o[jo] = f32x4{0.f, 0.f, 0.f, 0.f};
    float m_run[4], l_run[4];
    #pragma unroll
    for (int r = 0; r < 4; ++r) { m_run[r] = -INFINITY; l_run[r] = 0.f; }

    const int nt = (q0 >> 6) + 1;
    for (int t = 0; t < nt; ++t) {
        const int kv0 = t * 64;
        f32x4 s[4];
        #pragma unroll
        for (int jk = 0; jk < 4; ++jk) s[jk] = f32x4{0.f, 0.f, 0.f, 0.f};
        #pragma unroll
        for (int ds = 0; ds < 4; ++ds)
            #pragma unroll
            for (int jk = 0; jk < 4; ++jk) {
                bf16x8 bf = *(const bf16x8*)&kb[(size_t)(kv0 + jk * 16 + lc) * H_ + ds * 32 + gl * 8];
                s[jk] = __builtin_amdgcn_mfma_f32_16x16x32_bf16(aq[ds], bf, s[jk], 0, 0, 0);
            }
        if (kv0 + 63 > q0) {
            const int rowg = q0 + w * 16 + gl * 4;
            #pragma unroll
            for (int jk = 0; jk < 4; ++jk)
                #pragma unroll
                for (int r = 0; r < 4; ++r)
                    if (kv0 + jk * 16 + lc > rowg + r) s[jk][r] = -1e30f;
        }
        float pm[4];
        #pragma unroll
        for (int r = 0; r < 4; ++r)
            pm[r] = fmaxf(fmaxf(s[0][r], s[1][r]), fmaxf(s[2][r], s[3][r]));
        #pragma unroll
        for (int off = 1; off < 16; off <<= 1)
            #pragma unroll
            for (int r = 0; r < 4; ++r)
                pm[r] = fmaxf(pm[r], __shfl_xor(pm[r], off, 64));
        float scl[4], rs[4];
        #pragma unroll
        for (int r = 0; r < 4; ++r) {
            float mn = fmaxf(m_run[r], pm[r]);
            scl[r] = exp2f(m_run[r] - mn);
            m_run[r] = mn;
            rs[r] = 0.f;
        }
        #pragma unroll
        for (int jk = 0; jk < 4; ++jk)
            #pragma unroll
            for (int r = 0; r < 4; ++r) {
                float p = exp2f(s[jk][r] - m_run[r]);
                s[jk][r] = p;
                rs[r] += p;
            }
        #pragma unroll
        for (int off = 1; off < 16; off <<= 1)
            #pragma unroll
            for (int r = 0; r < 4; ++r)
                rs[r] += __shfl_xor(rs[r], off, 64);
        #pragma unroll
        for (int r = 0; r < 4; ++r)
            l_run[r] = l_run[r] * scl[r] + rs[r];
        #pragma unroll
        for (int jo = 0; jo < 8; ++jo)
            #pragma unroll
            for (int r = 0; r < 4; ++r)
                o[jo][r] *= scl[r];
        #pragma unroll
        for (int jk = 0; jk < 4; ++jk)
            #pragma unroll
            for (int r = 0; r < 4; ++r) {
                int row = gl * 4 + r;
                Ps[w][(row * 64 + jk * 16 + lc) ^ ((row & 7) << 3)] = f2bf(s[jk][r]);
            }
        #pragma unroll
        for (int ks = 0; ks < 2; ++ks) {
            bf16x8 pa = *(const bf16x8*)&Ps[w][(lc * 64 + ks * 32 + gl * 8) ^ ((lc & 7) << 3)];
            #pragma unroll
            for (int jo = 0; jo < 8; ++jo) {
                bf16x8 bv_ = *(const bf16x8*)&vb[(size_t)(jo * 16 + lc) * T_ + kv0 + ks * 32 + gl * 8];
                o[jo] = __builtin_amdgcn_mfma_f32_16x16x32_bf16(pa, bv_, o[jo], 0, 0, 0);
            }
        }
    }
    float* ob = out + (size_t)bb * T_ * H_;
    #pragma unroll
    for (int jo = 0; jo < 8; ++jo)
        #pragma unroll
        for (int r = 0; r < 4; ++r)
            ob[(size_t)(q0 + w * 16 + gl * 4 + r) * H_ + jo * 16 + lc] = o[jo][r] / l_run[r];
}

extern "C" void kernel_launch(void* const* d_in, const int* in_sizes, int n_in,
                              void* d_out, int out_size, void* d_ws, size_t ws_size,
                              hipStream_t stream) {
    const float* x  = (const float*)d_in[0];
    const float* Wq = (const float*)d_in[1];
    const float* bq = (const float*)d_in[2];
    const float* Wk = (const float*)d_in[3];
    const float* bk = (const float*)d_in[4];
    const float* Wv = (const float*)d_in[5];
    const float* bv = (const float*)d_in[6];
    float* out = (float*)d_out;

    const size_t qkv = (size_t)B_ * T_ * H_;               // 2M elems
    unsigned short* qws = (unsigned short*)d_ws;
    unsigned short* kws = qws + qkv;
    unsigned short* vws = kws + qkv;                       // [B,H,T] transposed
    unsigned short* wtw = vws + qkv;                       // [3,H,C]
    const size_t base_bytes = (3 * qkv + (size_t)3 * H_ * C_) * 2;  // 13,369,344
    unsigned short* Opart = (unsigned short*)((char*)d_ws + base_bytes);  // 1120 x 8192 bf16
    float* lws = (float*)((char*)d_ws + base_bytes + (size_t)1120 * 8192 * 2);
    const size_t need = base_bytes + (size_t)1120 * 8192 * 2 + (size_t)1120 * 64 * 4;

    prep_w<<<dim3(192), 256, 0, stream>>>(Wq, Wk, Wv, wtw);
    proj_fused4<<<dim3(256, 2), 256, 0, stream>>>(x, wtw, bq, bk, bv, qws, kws, vws);
    if (ws_size >= need) {
        attn_split7<<<dim3(8, 144), 256, 0, stream>>>(qws, kws, vws, out, Opart, lws);
        combine_kernel<<<dim3(3584), 256, 0, stream>>>(Opart, lws, out);
    } else {
        attn_mono<<<dim3(64, 8), 128, 0, stream>>>(qws, kws, vws, out);
    }
}

// Round 14
// 69.311 us; speedup vs baseline: 1.1298x; 1.0034x over previous
//
#include <hip/hip_runtime.h>
#include <cstdint>
#include <cstddef>

typedef __bf16 bf16x8 __attribute__((ext_vector_type(8)));
typedef float f32x4 __attribute__((ext_vector_type(4)));

#define B_ 8
#define T_ 2048
#define C_ 1024
#define H_ 128

// C^-0.5 * log2(e): folded into Q at projection; softmax runs in exp2-space.
#define QSC 0.045084220027780106f

__device__ __forceinline__ unsigned short f2bf(float f) {
    __bf16 h = (__bf16)f;
    return *(unsigned short*)&h;
}
__device__ __forceinline__ float bf2f(unsigned short u) {
    union { unsigned int i; float f; } x; x.i = ((unsigned int)u) << 16;
    return x.f;
}

// async global->LDS, 16B per lane. LDS dest must be the wave-uniform base;
// HW adds lane*16. Global src is per-lane.
__device__ __forceinline__ void gload16(void* lds, const void* g) {
    __builtin_amdgcn_global_load_lds(
        (const __attribute__((address_space(1))) unsigned int*)g,
        (__attribute__((address_space(3))) unsigned int*)lds, 16, 0, 0);
}

// ---------------------------------------------------------------------------
// prep_w: WT[which][n][k] bf16  <-  W[k][n] f32.  Row index R = which*128+n.
// ---------------------------------------------------------------------------
__global__ __launch_bounds__(256) void prep_w(
    const float* __restrict__ Wq, const float* __restrict__ Wk,
    const float* __restrict__ Wv, unsigned short* __restrict__ wt)
{
    int gid = blockIdx.x * 256 + threadIdx.x;        // 49152 total
    int which = gid >> 14;
    int rem = gid & 16383;
    int n = rem >> 7;            // 0..127
    int kc = rem & 127;          // k-chunk of 8
    const float* W = which == 0 ? Wq : (which == 1 ? Wk : Wv);
    unsigned short tmp[8];
    #pragma unroll
    for (int i = 0; i < 8; ++i) tmp[i] = f2bf(W[(size_t)(kc * 8 + i) * H_ + n]);
    *(uint4*)&wt[((size_t)which * H_ + n) * C_ + kc * 8] = *(uint4*)tmp;
}

// ---------------------------------------------------------------------------
// proj_fused5: 2-family fused projection with REG-STAGED BF16 x.
// Family f computes cols [f*192, f*192+192) of q|k|v for one 64-row m-tile.
// BM=64, BN=192, BK=64. 256 threads = 4 waves, each wave 64 rows x 48 cols
// (4x3 fragments). x: global f32 -> regs (4 x float4/thread) -> cvt -> bf16
// ds_write_b128 (T14 async split; A-fragments are single b128 reads, no cvt
// in the K-loop). W: gload16 counted-vmcnt. Per chunk per thread exactly
// 4 x-loads + 6 W-gloads: vmcnt(6)=x landed, vmcnt(10)=prev W landed.
// LDS: xs bf16 dbuf 16KB + W^T dbuf 48KB = 64KB -> 2 blocks/CU. Grid (256,2).
// Epilogue: acc -> LDS (stride 200) -> coalesced stores; Q scaled by QSC,
// V stored transposed [B,H,T].
// ---------------------------------------------------------------------------
__global__ __launch_bounds__(256, 2) void proj_fused5(
    const float* __restrict__ x, const unsigned short* __restrict__ wt,
    const float* __restrict__ bq, const float* __restrict__ bk,
    const float* __restrict__ bv,
    unsigned short* __restrict__ qo, unsigned short* __restrict__ ko,
    unsigned short* __restrict__ vo)
{
    __shared__ unsigned short smem[32768];       // 64 KB
    // xs(buf) = smem + buf*4096            [64 rows][8 chunks of 8 bf16], swz
    // ws(buf) = smem + 8192 + buf*12288    [192 R ][8 chunks of 8 bf16], swz
    // eb      = smem                       [64][200] epilogue (after K-loop)

    const int tid = threadIdx.x;
    const int w = tid >> 6, l = tid & 63, gl = l >> 4, lc = l & 15;
    const int cb = w * 48;           // wave's col band within the family
    const int fam = blockIdx.y;
    const int m0 = blockIdx.x * 64;
    const unsigned short* wbase = wt + (size_t)fam * 192 * C_;

    // x reg-staging geometry: thread -> (row sr, k-quarter q4 of 16 f32)
    const int sr = tid >> 2, q4 = tid & 3;
    const float* xrow = &x[(size_t)(m0 + sr) * C_ + q4 * 16];
    unsigned short* xw0;
    unsigned short* xw1;
    {
        int c0 = q4 * 2;
        // write targets recomputed per buf below (swizzle fixed per thread)
        (void)c0;
    }

    f32x4 acc[4][3];
    #pragma unroll
    for (int im = 0; im < 4; ++im)
        #pragma unroll
        for (int jn = 0; jn < 3; ++jn) acc[im][jn] = f32x4{0.f, 0.f, 0.f, 0.f};

    float xr[16];
    auto load_x = [&](int kc2) {                  // 4 global f32x4 loads
        const float* p = xrow + kc2 * 64;
        #pragma unroll
        for (int i = 0; i < 4; ++i) {
            float4 v4 = *(const float4*)(p + 4 * i);
            xr[4 * i + 0] = v4.x; xr[4 * i + 1] = v4.y;
            xr[4 * i + 2] = v4.z; xr[4 * i + 3] = v4.w;
        }
    };
    auto write_x = [&](int buf) {                 // cvt + 2 ds_write_b128
        unsigned short tb[16];
        #pragma unroll
        for (int i = 0; i < 16; ++i) tb[i] = f2bf(xr[i]);
        unsigned short* xb = smem + buf * 4096;
        const int c0 = q4 * 2;
        *(uint4*)&xb[(sr * 8 + ((c0 + 0) ^ (sr & 7))) * 8] = *(uint4*)&tb[0];
        *(uint4*)&xb[(sr * 8 + ((c0 + 1) ^ (sr & 7))) * 8] = *(uint4*)&tb[8];
    };
    auto stage_w = [&](int buf, int kc2) {        // 6 gload16 per thread
        const int kb = kc2 * 64;
        unsigned short* wb = smem + 8192 + buf * 12288;
        #pragma unroll
        for (int ji = 0; ji < 6; ++ji) {
            int slot = ji * 256 + tid;
            int R = slot >> 3, cs = slot & 7;
            gload16(&wb[(ji * 256 + w * 64) * 8],
                    &wbase[(size_t)R * C_ + kb + ((cs ^ (R & 7)) * 8)]);
        }
    };

    // ---- prologue
    load_x(0);                                    // 4 loads
    stage_w(0, 0);                                // 6 gloads   (outstanding 10)
    asm volatile("s_waitcnt vmcnt(6)" ::: "memory");   // x0 landed
    __builtin_amdgcn_sched_barrier(0);
    write_x(0);
    load_x(1);
    stage_w(1, 1);                                // outstanding: W0 6 + 10
    asm volatile("s_waitcnt vmcnt(10)" ::: "memory");  // W0 landed
    __builtin_amdgcn_sched_barrier(0);
    asm volatile("s_waitcnt lgkmcnt(0)" ::: "memory");
    __builtin_amdgcn_sched_barrier(0);
    __builtin_amdgcn_s_barrier();

    for (int kc = 0; kc < 16; ++kc) {
        const int cur = kc & 1, nxt = cur ^ 1;
        const unsigned short* xb = smem + cur * 4096;
        const unsigned short* wb = smem + 8192 + cur * 12288;
        #pragma unroll
        for (int ks = 0; ks < 2; ++ks) {
            bf16x8 a[4], b[3];
            const int u = ks * 4 + gl;
            #pragma unroll
            for (int im = 0; im < 4; ++im) {
                int row = im * 16 + lc;            // row & 7 == lc & 7
                a[im] = *(const bf16x8*)&xb[(row * 8 + (u ^ (lc & 7))) * 8];
            }
            #pragma unroll
            for (int jn = 0; jn < 3; ++jn) {
                int R = cb + jn * 16 + lc;         // R & 7 == lc & 7
                b[jn] = *(const bf16x8*)&wb[(R * 8 + (u ^ (lc & 7))) * 8];
            }
            #pragma unroll
            for (int im = 0; im < 4; ++im)
                #pragma unroll
                for (int jn = 0; jn < 3; ++jn)
                    acc[im][jn] = __builtin_amdgcn_mfma_f32_16x16x32_bf16(
                        a[im], b[jn], acc[im][jn], 0, 0, 0);
        }
        // barrier #1: all waves done reading buf cur
        __builtin_amdgcn_s_barrier();
        if (kc < 14) {
            asm volatile("s_waitcnt vmcnt(6)" ::: "memory");   // x(kc+1) in regs
            __builtin_amdgcn_sched_barrier(0);
            write_x(nxt);                          // chunk kc+1 -> xs[nxt]
            load_x(kc + 2);                        // 4 loads
            stage_w(cur, kc + 2);                  // 6 gloads -> ws[cur]
            asm volatile("s_waitcnt vmcnt(10)" ::: "memory");  // W(kc+1) landed
            __builtin_amdgcn_sched_barrier(0);
            asm volatile("s_waitcnt lgkmcnt(0)" ::: "memory"); // ds_writes done
            __builtin_amdgcn_sched_barrier(0);
            __builtin_amdgcn_s_barrier();          // barrier #2
        } else if (kc == 14) {
            asm volatile("s_waitcnt vmcnt(6)" ::: "memory");   // x15 in regs
            __builtin_amdgcn_sched_barrier(0);
            write_x(nxt);                          // chunk 15 -> xs[1]
            asm volatile("s_waitcnt vmcnt(0)" ::: "memory");   // W15 landed
            __builtin_amdgcn_sched_barrier(0);
            asm volatile("s_waitcnt lgkmcnt(0)" ::: "memory");
            __builtin_amdgcn_sched_barrier(0);
            __builtin_amdgcn_s_barrier();
        }
        // kc == 15: barrier #1 already passed -> epilogue
    }

    // epilogue: acc -> eb (bf16, stride 200 = 192+8 for bank spread)
    unsigned short* eb = smem;                     // 64*200 = 12800 ushort
    #pragma unroll
    for (int jn = 0; jn < 3; ++jn) {
        int nl_ = cb + jn * 16 + lc;               // 0..191 (family-local)
        int ng = fam * 192 + nl_;                  // 0..383 global col
        int wh = ng >> 7, nn = ng & 127;
        float bb = (wh == 0) ? bq[nn] : (wh == 1 ? bk[nn] : bv[nn]);
        float sc = (wh == 0) ? QSC : 1.0f;
        #pragma unroll
        for (int im = 0; im < 4; ++im)
            #pragma unroll
            for (int r = 0; r < 4; ++r) {
                int row = im * 16 + gl * 4 + r;
                eb[row * 200 + nl_] = f2bf((acc[im][jn][r] + bb) * sc);
            }
    }
    __syncthreads();

    const int bi = m0 >> 11, t0 = m0 & (T_ - 1);
    if (fam == 0) {
        // q full (cols 0..127): 1024 uint4
        #pragma unroll
        for (int i = 0; i < 4; ++i) {
            int c = i * 256 + tid;
            int row = c >> 4, c16 = c & 15;
            *(uint4*)&qo[(size_t)(m0 + row) * H_ + c16 * 8] =
                *(const uint4*)&eb[row * 200 + c16 * 8];
        }
        // k cols 0..63 (eb cols 128..191): 512 uint4
        #pragma unroll
        for (int i = 0; i < 2; ++i) {
            int c = i * 256 + tid;
            int row = c >> 3, c8 = c & 7;
            *(uint4*)&ko[(size_t)(m0 + row) * H_ + c8 * 8] =
                *(const uint4*)&eb[row * 200 + 128 + c8 * 8];
        }
    } else {
        // k cols 64..127 (eb cols 0..63): 512 uint4
        #pragma unroll
        for (int i = 0; i < 2; ++i) {
            int c = i * 256 + tid;
            int row = c >> 3, c8 = c & 7;
            *(uint4*)&ko[(size_t)(m0 + row) * H_ + 64 + c8 * 8] =
                *(const uint4*)&eb[row * 200 + c8 * 8];
        }
        // v (cols 256..383 -> eb cols 64..191), stored transposed
        #pragma unroll
        for (int i = 0; i < 4; ++i) {
            int c = i * 256 + tid;
            int n = c >> 3, cc = c & 7;
            unsigned short tmp[8];
            #pragma unroll
            for (int ii = 0; ii < 8; ++ii)
                tmp[ii] = eb[(cc * 8 + ii) * 200 + 64 + n];
            *(uint4*)&vo[((size_t)(bi * H_ + n)) * T_ + t0 + cc * 8] = *(uint4*)tmp;
        }
    }
}

// pasc(qt) = number of jobs for q-tiles < qt (QBLK=64, chunk=256):
// nch(i) = ceil((i+1)/4); pasc = 2m(m+1) + j(m+1), m=qt>>2, j=qt&3.
__device__ __forceinline__ int pasc(int qt) {
    int m = qt >> 2, j = qt & 3;
    return 2 * m * (m + 1) + j * (m + 1);
}

// ---------------------------------------------------------------------------
// attn_split7: KV-split flash attention, 4 waves (QBLK=64) sharing K/V LDS.
// grid (8 batch=XCD pin, 144 jobs). KVBLK=32, chunk=256 keys.
// LDS = 16+16+8 = 40KB -> 4 blocks/CU = 16 waves/CU resident.
// No-max exp2 softmax; bf16 partials; plain-sum combine.
// ---------------------------------------------------------------------------
__global__ __launch_bounds__(256, 2) void attn_split7(
    const unsigned short* __restrict__ q,
    const unsigned short* __restrict__ k,
    const unsigned short* __restrict__ vT,
    float* __restrict__ out,
    unsigned short* __restrict__ Opart, float* __restrict__ lws)
{
    const int bb = blockIdx.x;                 // batch -> XCD pin
    const int jj = 143 - (int)blockIdx.y;      // longest jobs first
    int qt = 31;
    while (pasc(qt) > jj) --qt;
    const int c = jj - pasc(qt);
    const int nch = (qt >> 2) + 1;
    const int q0 = qt * 64;
    const int kstart = c * 256;
    const int kend = min(kstart + 256, q0 + 64);
    const int ntiles = (kend - kstart) >> 5;   // 1..8

    const unsigned short* qb = q  + (size_t)bb * T_ * H_;
    const unsigned short* kb = k  + (size_t)bb * T_ * H_;
    const unsigned short* vb = vT + (size_t)bb * H_ * T_;

    __shared__ unsigned short Ks[2][32 * 128];   // [key][d], chunk-XOR swizzled
    __shared__ unsigned short Vs[2][128 * 32];   // [d][key], chunk-XOR swizzled
    __shared__ unsigned short Ps[4][16 * 64];    // per-wave P

    const int tid = threadIdx.x;
    const int w = tid >> 6, l = tid & 63, gl = l >> 4, lc = l & 15;
    const int rowbase = q0 + w * 16;             // this wave's first q row

    bf16x8 aq[4];
    #pragma unroll
    for (int ds = 0; ds < 4; ++ds)
        aq[ds] = *(const bf16x8*)&qb[(size_t)(rowbase + lc) * H_ + ds * 32 + gl * 8];

    f32x4 o[8];
    #pragma unroll
    for (int jo = 0; jo < 8; ++jo) o[jo] = f32x4{0.f, 0.f, 0.f, 0.f};
    float l_acc[4];
    #pragma unroll
    for (int r = 0; r < 4; ++r) l_acc[r] = 0.f;

    auto stageK = [&](int buf, int t) {
        const int kv0 = kstart + t * 32;
        #pragma unroll
        for (int ji = 0; ji < 2; ++ji) {
            int slot = (w * 2 + ji) * 64 + l;
            int r = slot >> 4, cs = slot & 15;
            gload16(&Ks[buf][((w * 2 + ji) * 64) * 8],
                    &kb[(size_t)(kv0 + r) * H_ + ((cs ^ (r & 7)) * 8)]);
        }
    };
    auto stageV = [&](int buf, int t) {
        const int kv0 = kstart + t * 32;
        #pragma unroll
        for (int ji = 0; ji < 2; ++ji) {
            int slot = (w * 2 + ji) * 64 + l;
            int r = slot >> 2, cs = slot & 3;
            gload16(&Vs[buf][((w * 2 + ji) * 64) * 8],
                    &vb[(size_t)r * T_ + kv0 + ((cs ^ (r & 3)) * 8)]);
        }
    };

    stageK(0, 0);
    stageV(0, 0);
    __syncthreads();

    int cur = 0;
    for (int t = 0; t < ntiles; ++t) {
        if (t + 1 < ntiles) { stageK(cur ^ 1, t + 1); stageV(cur ^ 1, t + 1); }
        const int kv0 = kstart + t * 32;
        const bool active = kv0 < rowbase + 16;
        if (active) {
            f32x4 s[2];
            #pragma unroll
            for (int jk = 0; jk < 2; ++jk) s[jk] = f32x4{0.f, 0.f, 0.f, 0.f};
            #pragma unroll
            for (int ds = 0; ds < 4; ++ds) {
                #pragma unroll
                for (int jk = 0; jk < 2; ++jk) {
                    int row = jk * 16 + lc;
                    bf16x8 kf = *(const bf16x8*)&Ks[cur][(row * 16 + ((ds * 4 + gl) ^ (row & 7))) * 8];
                    s[jk] = __builtin_amdgcn_mfma_f32_16x16x32_bf16(aq[ds], kf, s[jk], 0, 0, 0);
                }
            }
            if (kv0 + 31 > rowbase) {
                #pragma unroll
                for (int jk = 0; jk < 2; ++jk)
                    #pragma unroll
                    for (int r = 0; r < 4; ++r)
                        if (kv0 + jk * 16 + lc > rowbase + gl * 4 + r) s[jk][r] = -1e30f;
            }
            #pragma unroll
            for (int jk = 0; jk < 2; ++jk)
                #pragma unroll
                for (int r = 0; r < 4; ++r) {
                    float p = exp2f(fminf(s[jk][r], 80.f));
                    s[jk][r] = p;
                    l_acc[r] += p;
                }
            #pragma unroll
            for (int jk = 0; jk < 2; ++jk)
                #pragma unroll
                for (int r = 0; r < 4; ++r) {
                    int row = gl * 4 + r;
                    Ps[w][(row * 64 + jk * 16 + lc) ^ ((row & 7) << 3)] = f2bf(s[jk][r]);
                }
            {
                bf16x8 pa = *(const bf16x8*)&Ps[w][(lc * 64 + gl * 8) ^ ((lc & 7) << 3)];
                #pragma unroll
                for (int jo = 0; jo < 8; ++jo) {
                    int d = jo * 16 + lc;
                    bf16x8 vf = *(const bf16x8*)&Vs[cur][(d * 4 + (gl ^ (d & 3))) * 8];
                    o[jo] = __builtin_amdgcn_mfma_f32_16x16x32_bf16(pa, vf, o[jo], 0, 0, 0);
                }
            }
        }
        __syncthreads();
        cur ^= 1;
    }

    #pragma unroll
    for (int off = 1; off < 16; off <<= 1)
        #pragma unroll
        for (int r = 0; r < 4; ++r)
            l_acc[r] += __shfl_xor(l_acc[r], off, 64);

    if (nch == 1) {
        float* ob = out + (size_t)bb * T_ * H_;
        float inv[4];
        #pragma unroll
        for (int r = 0; r < 4; ++r) inv[r] = 1.0f / l_acc[r];
        #pragma unroll
        for (int jo = 0; jo < 8; ++jo)
            #pragma unroll
            for (int r = 0; r < 4; ++r)
                ob[(size_t)(rowbase + gl * 4 + r) * H_ + jo * 16 + lc] = o[jo][r] * inv[r];
    } else {
        const int slot = bb * 140 + (pasc(qt) - 4 + c);
        unsigned short* op = Opart + (size_t)slot * 8192;
        #pragma unroll
        for (int jo = 0; jo < 8; ++jo)
            #pragma unroll
            for (int r = 0; r < 4; ++r)
                op[(w * 16 + gl * 4 + r) * 128 + jo * 16 + lc] = f2bf(o[jo][r]);
        if (lc == 0) {
            #pragma unroll
            for (int r = 0; r < 4; ++r)
                lws[slot * 64 + w * 16 + gl * 4 + r] = l_acc[r];
        }
    }
}

// ---------------------------------------------------------------------------
// combine: out[t] = sum_c O_c[t] / sum_c l_c[t] for t >= 256 (bf16 partials).
// ---------------------------------------------------------------------------
__global__ __launch_bounds__(256) void combine_kernel(
    const unsigned short* __restrict__ Opart, const float* __restrict__ lws,
    float* __restrict__ out)
{
    const int rowid = blockIdx.x * 4 + (threadIdx.x >> 6);   // 0..14335
    const int lane = threadIdx.x & 63;
    const int bb = rowid / 1792;
    const int t = 256 + (rowid - bb * 1792);                 // 256..2047
    const int qt = t >> 6;                                    // 4..31
    const int m = qt >> 2;
    const int nch = m + 1;
    const int p0 = 2 * m * (m + 1) + (qt & 3) * (m + 1);     // pasc(qt)
    const int base = bb * 140 + (p0 - 4);
    const int r64 = t & 63;

    float L = 0.f, a0 = 0.f, a1 = 0.f;
    #pragma unroll
    for (int c2 = 0; c2 < 8; ++c2)
        if (c2 < nch) {
            L += lws[(base + c2) * 64 + r64];
            ushort2 uv = *(const ushort2*)&Opart[(size_t)(base + c2) * 8192 + r64 * 128 + lane * 2];
            a0 += bf2f(uv.x); a1 += bf2f(uv.y);
        }
    const float invL = 1.0f / L;
    *(float2*)&out[((size_t)bb * T_ + t) * H_ + lane * 2] = make_float2(a0 * invL, a1 * invL);
}

// ---------------------------------------------------------------------------
// Fallback monolithic attention (only if ws too small). Max-tracking version.
// ---------------------------------------------------------------------------
__global__ __launch_bounds__(128) void attn_mono(
    const unsigned short* __restrict__ q,
    const unsigned short* __restrict__ k,
    const unsigned short* __restrict__ vT,
    float* __restrict__ out)
{
    const int qt = (gridDim.x - 1) - blockIdx.x;
    const int bb = blockIdx.y;
    const int q0 = qt * 32;
    const unsigned short* qb = q  + (size_t)bb * T_ * H_;
    const unsigned short* kb = k  + (size_t)bb * T_ * H_;
    const unsigned short* vb = vT + (size_t)bb * H_ * T_;

    __shared__ unsigned short Ps[2][16 * 64];

    const int tid = threadIdx.x;
    const int w = tid >> 6, l = tid & 63, gl = l >> 4, lc = l & 15;

    bf16x8 aq[4];
    #pragma unroll
    for (int ds = 0; ds < 4; ++ds)
        aq[ds] = *(const bf16x8*)&qb[(size_t)(q0 + w * 16 + lc) * H_ + ds * 32 + gl * 8];

    f32x4 o[8];
    #pragma unroll
    for (int jo = 0; jo < 8; ++jo) o[jo] = f32x4{0.f, 0.f, 0.f, 0.f};
    float m_run[4], l_run[4];
    #pragma unroll
    for (int r = 0; r < 4; ++r) { m_run[r] = -INFINITY; l_run[r] = 0.f; }

    const int nt = (q0 >> 6) + 1;
    for (int t = 0; t < nt; ++t) {
        const int kv0 = t * 64;
        f32x4 s[4];
        #pragma unroll
        for (int jk = 0; jk < 4; ++jk) s[jk] = f32x4{0.f, 0.f, 0.f, 0.f};
        #pragma unroll
        for (int ds = 0; ds < 4; ++ds)
            #pragma unroll
            for (int jk = 0; jk < 4; ++jk) {
                bf16x8 bf = *(const bf16x8*)&kb[(size_t)(kv0 + jk * 16 + lc) * H_ + ds * 32 + gl * 8];
                s[jk] = __builtin_amdgcn_mfma_f32_16x16x32_bf16(aq[ds], bf, s[jk], 0, 0, 0);
            }
        if (kv0 + 63 > q0) {
            const int rowg = q0 + w * 16 + gl * 4;
            #pragma unroll
            for (int jk = 0; jk < 4; ++jk)
                #pragma unroll
                for (int r = 0; r < 4; ++r)
                    if (kv0 + jk * 16 + lc > rowg + r) s[jk][r] = -1e30f;
        }
        float pm[4];
        #pragma unroll
        for (int r = 0; r < 4; ++r)
            pm[r] = fmaxf(fmaxf(s[0][r], s[1][r]), fmaxf(s[2][r], s[3][r]));
        #pragma unroll
        for (int off = 1; off < 16; off <<= 1)
            #pragma unroll
            for (int r = 0; r < 4; ++r)
                pm[r] = fmaxf(pm[r], __shfl_xor(pm[r], off, 64));
        float scl[4], rs[4];
        #pragma unroll
        for (int r = 0; r < 4; ++r) {
            float mn = fmaxf(m_run[r], pm[r]);
            scl[r] = exp2f(m_run[r] - mn);
            m_run[r] = mn;
            rs[r] = 0.f;
        }
        #pragma unroll
        for (int jk = 0; jk < 4; ++jk)
            #pragma unroll
            for (int r = 0; r < 4; ++r) {
                float p = exp2f(s[jk][r] - m_run[r]);
                s[jk][r] = p;
                rs[r] += p;
            }
        #pragma unroll
        for (int off = 1; off < 16; off <<= 1)
            #pragma unroll
            for (int r = 0; r < 4; ++r)
                rs[r] += __shfl_xor(rs[r], off, 64);
        #pragma unroll
        for (int r = 0; r < 4; ++r)
            l_run[r] = l_run[r] * scl[r] + rs[r];
        #pragma unroll
        for (int jo = 0; jo < 8; ++jo)
            #pragma unroll
            for (int r = 0; r < 4; ++r)
                o[jo][r] *= scl[r];
        #pragma unroll
        for (int jk = 0; jk < 4; ++jk)
            #pragma unroll
            for (int r = 0; r < 4; ++r) {
                int row = gl * 4 + r;
                Ps[w][(row * 64 + jk * 16 + lc) ^ ((row & 7) << 3)] = f2bf(s[jk][r]);
            }
        #pragma unroll
        for (int ks = 0; ks < 2; ++ks) {
            bf16x8 pa = *(const bf16x8*)&Ps[w][(lc * 64 + ks * 32 + gl * 8) ^ ((lc & 7) << 3)];
            #pragma unroll
            for (int jo = 0; jo < 8; ++jo) {
                bf16x8 bv_ = *(const bf16x8*)&vb[(size_t)(jo * 16 + lc) * T_ + kv0 + ks * 32 + gl * 8];
                o[jo] = __builtin_amdgcn_mfma_f32_16x16x32_bf16(pa, bv_, o[jo], 0, 0, 0);
            }
        }
    }
    float* ob = out + (size_t)bb * T_ * H_;
    #pragma unroll
    for (int jo = 0; jo < 8; ++jo)
        #pragma unroll
        for (int r = 0; r < 4; ++r)
            ob[(size_t)(q0 + w * 16 + gl * 4 + r) * H_ + jo * 16 + lc] = o[jo][r] / l_run[r];
}

extern "C" void kernel_launch(void* const* d_in, const int* in_sizes, int n_in,
                              void* d_out, int out_size, void* d_ws, size_t ws_size,
                              hipStream_t stream) {
    const float* x  = (const float*)d_in[0];
    const float* Wq = (const float*)d_in[1];
    const float* bq = (const float*)d_in[2];
    const float* Wk = (const float*)d_in[3];
    const float* bk = (const float*)d_in[4];
    const float* Wv = (const float*)d_in[5];
    const float* bv = (const float*)d_in[6];
    float* out = (float*)d_out;

    const size_t qkv = (size_t)B_ * T_ * H_;               // 2M elems
    unsigned short* qws = (unsigned short*)d_ws;
    unsigned short* kws = qws + qkv;
    unsigned short* vws = kws + qkv;                       // [B,H,T] transposed
    unsigned short* wtw = vws + qkv;                       // [3,H,C]
    const size_t base_bytes = (3 * qkv + (size_t)3 * H_ * C_) * 2;  // 13,369,344
    unsigned short* Opart = (unsigned short*)((char*)d_ws + base_bytes);  // 1120 x 8192 bf16
    float* lws = (float*)((char*)d_ws + base_bytes + (size_t)1120 * 8192 * 2);
    const size_t need = base_bytes + (size_t)1120 * 8192 * 2 + (size_t)1120 * 64 * 4;

    prep_w<<<dim3(192), 256, 0, stream>>>(Wq, Wk, Wv, wtw);
    proj_fused5<<<dim3(256, 2), 256, 0, stream>>>(x, wtw, bq, bk, bv, qws, kws, vws);
    if (ws_size >= need) {
        attn_split7<<<dim3(8, 144), 256, 0, stream>>>(qws, kws, vws, out, Opart, lws);
        combine_kernel<<<dim3(3584), 256, 0, stream>>>(Opart, lws, out);
    } else {
        attn_mono<<<dim3(64, 8), 128, 0, stream>>>(qws, kws, vws, out);
    }
}